// Round 7
// baseline (384.266 us; speedup 1.0000x reference)
//
#include <hip/hip_runtime.h>
#include <stdint.h>

// ---------------------------------------------------------------------------
// BitAttention round 7:
//   - flash_attn v7: ZERO-barrier, ZERO-staging attention. K and V^T frags
//     read directly from global (L1/L2-shared across the 8 waves/block);
//     512-thread blocks, 8 waves x 16 q-rows, each wave runs both paired
//     q-tiles (uniform 34 units) -> 16 waves/CU. lP is wave-private LDS.
//     XCD swizzle pins each (b,kv) group's K/V^T to one XCD's L2.
//   - gemm_bt VSPLIT -> vt[512][4096] (V transposed), Q pre-scaled (kept)
// ws layout (bytes):
//   [0,5120)    double partials[640]
//   [6144,6304) float tabs[40]
//   [8192,...)  xb(16M) wqkvs(12M) wos(8M) qkvb(24M) ao(16M) vt(4M)
// ---------------------------------------------------------------------------

#define D_MODEL 2048
#define S_LEN   2048
#define BATCH   2
#define NKV     8
#define HD      64
#define MROWS   (BATCH * S_LEN)   // 4096
#define NQKV    3072
#define LDQKV   3072

typedef unsigned short u16;
typedef __bf16 bf16x8 __attribute__((ext_vector_type(8)));
typedef float  f32x4  __attribute__((ext_vector_type(4)));

__device__ __forceinline__ u16 f2bf(float f) {
  union { float f; unsigned u; } v; v.f = f;
  unsigned r = v.u + 0x7FFFu + ((v.u >> 16) & 1u);   // RNE
  return (u16)(r >> 16);
}

__device__ __forceinline__ float exp2_fast(float x) {
  float r; asm("v_exp_f32 %0, %1" : "=v"(r) : "v"(x)); return r;
}

__device__ __forceinline__ unsigned cvt_pk_bf16(float a, float b) {
  unsigned r;
  asm("v_cvt_pk_bf16_f32 %0, %1, %2" : "=v"(r) : "v"(a), "v"(b));
  return r;
}

__device__ __forceinline__ void lds_load16(u16* lds, const u16* g) {
  __builtin_amdgcn_global_load_lds(
      (const __attribute__((address_space(1))) void*)g,
      (__attribute__((address_space(3))) void*)lds, 16, 0, 0);
}

#define SM_LOG2E 0.180336880f   // (1/sqrt(64)) * log2(e); folded into Q cols
#define THR_LOG2 11.5415603f    // 8 * log2(e)

// ---------------- fused prep: weight sign+|w| partials, x->bf16 ----------------
__global__ void prep_all(const float* __restrict__ wq, const float* __restrict__ wk,
                         const float* __restrict__ wv, const float* __restrict__ wo,
                         const float* __restrict__ x,
                         u16* __restrict__ wqkvs, u16* __restrict__ wos,
                         u16* __restrict__ xb, double* __restrict__ partials) {
  const int bid = blockIdx.x;
  const float* src; u16* dst; int n4, rb, nb; bool sgn = true;
  if (bid < 256)      { src = wq; dst = wqkvs;                  n4 = 1048576; rb = bid;       nb = 256; }
  else if (bid < 320) { src = wk; dst = wqkvs + 2048 * D_MODEL; n4 = 262144;  rb = bid - 256; nb = 64;  }
  else if (bid < 384) { src = wv; dst = wqkvs + 2560 * D_MODEL; n4 = 262144;  rb = bid - 320; nb = 64;  }
  else if (bid < 640) { src = wo; dst = wos;                    n4 = 1048576; rb = bid - 384; nb = 256; }
  else                { src = x;  dst = xb;                     n4 = 2097152; rb = bid - 640; nb = 512; sgn = false; }

  if (sgn) {
    double s = 0.0;
    for (int i = rb * 256 + threadIdx.x; i < n4; i += nb * 256) {
      float4 v = reinterpret_cast<const float4*>(src)[i];
      ushort4 o;
      o.x = v.x > 0.f ? 0x3F80 : (v.x < 0.f ? 0xBF80 : 0);
      o.y = v.y > 0.f ? 0x3F80 : (v.y < 0.f ? 0xBF80 : 0);
      o.z = v.z > 0.f ? 0x3F80 : (v.z < 0.f ? 0xBF80 : 0);
      o.w = v.w > 0.f ? 0x3F80 : (v.w < 0.f ? 0xBF80 : 0);
      reinterpret_cast<ushort4*>(dst)[i] = o;
      s += (double)fabsf(v.x) + (double)fabsf(v.y) +
           (double)fabsf(v.z) + (double)fabsf(v.w);
    }
    __shared__ double sm[256];
    sm[threadIdx.x] = s;
    __syncthreads();
    for (int off = 128; off > 0; off >>= 1) {
      if (threadIdx.x < off) sm[threadIdx.x] += sm[threadIdx.x + off];
      __syncthreads();
    }
    if (threadIdx.x == 0) partials[bid] = sm[0];
  } else {
    for (int i = rb * 256 + threadIdx.x; i < n4; i += nb * 256) {
      float4 v = reinterpret_cast<const float4*>(src)[i];
      ushort4 o;
      o.x = f2bf(v.x); o.y = f2bf(v.y); o.z = f2bf(v.z); o.w = f2bf(v.w);
      reinterpret_cast<ushort4*>(dst)[i] = o;
    }
  }
}

__global__ void finalize_scales(const double* __restrict__ partials,
                                float* __restrict__ tabs) {
  if (threadIdx.x == 0 && blockIdx.x == 0) {
    const int beg[4] = {0, 256, 320, 384};
    const int end[4] = {256, 320, 384, 640};
    const double counts[4] = {4194304.0, 1048576.0, 1048576.0, 4194304.0};
    float sc[4];
    for (int w = 0; w < 4; ++w) {
      double s = 0.0;
      for (int i = beg[w]; i < end[w]; ++i) s += partials[i];
      sc[w] = fmaxf((float)(s / counts[w]), 1e-5f);
    }
    for (int i = 0; i < 24; ++i)
      tabs[i] = (i < 16) ? sc[0] * SM_LOG2E : (i < 20 ? sc[1] : sc[2]);
    for (int i = 0; i < 16; ++i) tabs[24 + i] = sc[3];
  }
}

// ---------------- GEMM: C[m,n] = tab[bx] * sum_k A[m,k]*Bt[n,k] ----------------
// VSPLIT: blocks with bx>=20 (V columns) store TRANSPOSED into vt[512][4096].
template <int OUT_BF16, int VSPLIT>
__global__ __launch_bounds__(256, 2) void gemm_bt(
    const u16* __restrict__ A, const u16* __restrict__ Bt, void* __restrict__ Cv,
    const float* __restrict__ tab, u16* __restrict__ vt, int M, int N, int K) {
  __shared__ u16 lA[128 * 64];
  __shared__ u16 lB[128 * 64];
  const int tid = threadIdx.x;
  const int lane = tid & 63, wave = tid >> 6;
  const int lo = lane & 15, hi = lane >> 4;
  const int m0 = blockIdx.y * 128, n0 = blockIdx.x * 128;
  const int wr = (wave >> 1) * 64, wc = (wave & 1) * 64;

  f32x4 acc[4][4] = {};

  for (int k0 = 0; k0 < K; k0 += 64) {
#pragma unroll
    for (int it = 0; it < 4; ++it) {
      const int c = it * 256 + wave * 64 + lane;
      const int row = c >> 3, kc = (c & 7) << 3;
      lds_load16(&lA[(it * 256 + wave * 64) * 8], &A[(size_t)(m0 + row) * K + k0 + kc]);
      lds_load16(&lB[(it * 256 + wave * 64) * 8], &Bt[(size_t)(n0 + row) * K + k0 + kc]);
    }
    __syncthreads();
#pragma unroll
    for (int kk = 0; kk < 2; ++kk) {
      bf16x8 af[4], bfr[4];
#pragma unroll
      for (int i = 0; i < 4; ++i)
        af[i] = *reinterpret_cast<const bf16x8*>(&lA[(wr + i * 16 + lo) * 64 + kk * 32 + hi * 8]);
#pragma unroll
      for (int i = 0; i < 4; ++i)
        bfr[i] = *reinterpret_cast<const bf16x8*>(&lB[(wc + i * 16 + lo) * 64 + kk * 32 + hi * 8]);
#pragma unroll
      for (int mi = 0; mi < 4; ++mi)
#pragma unroll
        for (int ni = 0; ni < 4; ++ni)
          acc[mi][ni] = __builtin_amdgcn_mfma_f32_16x16x32_bf16(af[mi], bfr[ni], acc[mi][ni], 0, 0, 0);
    }
    __syncthreads();
  }

  const float scale = tab[blockIdx.x];
  if (VSPLIT && (int)blockIdx.x >= 20) {
    // V columns: transposed store, 4 consecutive rows (m) packed per dwordx2
#pragma unroll
    for (int mi = 0; mi < 4; ++mi) {
#pragma unroll
      for (int ni = 0; ni < 4; ++ni) {
        const int col = (n0 - 2560) + wc + ni * 16 + lo;       // 0..511
        const int row = m0 + wr + mi * 16 + hi * 4;            // mult of 4
        unsigned w01 = (unsigned)f2bf(acc[mi][ni][0] * scale) |
                       ((unsigned)f2bf(acc[mi][ni][1] * scale) << 16);
        unsigned w23 = (unsigned)f2bf(acc[mi][ni][2] * scale) |
                       ((unsigned)f2bf(acc[mi][ni][3] * scale) << 16);
        uint2 pk; pk.x = w01; pk.y = w23;
        *reinterpret_cast<uint2*>(vt + (size_t)col * MROWS + row) = pk;
      }
    }
    return;
  }
#pragma unroll
  for (int mi = 0; mi < 4; ++mi) {
#pragma unroll
    for (int ni = 0; ni < 4; ++ni) {
#pragma unroll
      for (int r = 0; r < 4; ++r) {
        const int row = m0 + wr + mi * 16 + hi * 4 + r;
        const int col = n0 + wc + ni * 16 + lo;
        const float v = acc[mi][ni][r] * scale;
        if (OUT_BF16)
          reinterpret_cast<u16*>(Cv)[(size_t)row * N + col] = f2bf(v);
        else
          reinterpret_cast<float*>(Cv)[(size_t)row * N + col] = v;
      }
    }
  }
}

// ---------------- flash attention v7 (barrier-free, staging-free) ----------------
// grid (8,64) x 512 threads. XCD swizzle: (bx,by) -> lbx=by&7, lby=bx*8+by/8
// so each XCD hosts 8 complete (b,kv) groups (K+VT working set = 4MB = L2).
// Wave w handles 16 q-rows; runs q-tiles lbx then 15-lbx (34 units uniform).
__global__ __launch_bounds__(512, 4) void flash_attn(
    const u16* __restrict__ QKV, const u16* __restrict__ VT,
    u16* __restrict__ Og) {
  __shared__ u16 lP[8][16 * 72];    // per-wave P[q][t], stride 72

  const int tid = threadIdx.x;
  const int lane = tid & 63, wave = tid >> 6;
  const int lo = lane & 15, hi = lane >> 4;
  const int lbx = blockIdx.y & 7;
  const int lby = ((int)blockIdx.x << 3) | ((int)blockIdx.y >> 3);
  const int b = lby >> 5, h = lby & 31, kv = h >> 2;
  const int brow = b * S_LEN;
  const u16* Q  = QKV + h * HD;
  const u16* Kb = QKV + 2048 + kv * HD;                   // row stride LDQKV
  const u16* Vb = VT + (size_t)(kv * HD) * MROWS + brow;  // row d, stride MROWS
  const int xbase = (lane & 48) | ((lane >> 2) & 12);     // lane with lo=hi*4(+r)
  u16* lPw = (u16*)lP[wave];

#pragma unroll 1
  for (int pass = 0; pass < 2; ++pass) {
    const int qt = pass == 0 ? lbx : 15 - lbx;
    const int q0 = qt * 128;
    const int q0w = q0 + wave * 16;      // this wave's 16 q-rows
    const int nt = 2 * qt + 2;
    const int qg = q0w + lo;             // lane's q row (S^T col)

    // Q fragments (pre-scaled by sm_scale*log2e)
    bf16x8 qf[2];
    {
      const size_t qr = (size_t)(brow + q0w + lo) * LDQKV;
#pragma unroll
      for (int kk = 0; kk < 2; ++kk)
        qf[kk] = *reinterpret_cast<const bf16x8*>(&Q[qr + kk * 32 + hi * 8]);
    }

    f32x4 oacc[4] = {};
    float m_run = -1e30f, l_lane = 0.f;

#pragma unroll 1
    for (int ti = 0; ti < nt; ++ti) {
      const int t0 = ti * 64;

      // ---- S^T = K Q^T : lane holds q=lo, t = nf*16 + hi*4 + r ----
      f32x4 sacc[4] = {};
      __builtin_amdgcn_s_setprio(1);
#pragma unroll
      for (int kk = 0; kk < 2; ++kk) {
#pragma unroll
        for (int nf = 0; nf < 4; ++nf) {
          bf16x8 kf = *reinterpret_cast<const bf16x8*>(
              &Kb[(size_t)(brow + t0 + nf * 16 + lo) * LDQKV + kk * 32 + hi * 8]);
          sacc[nf] = __builtin_amdgcn_mfma_f32_16x16x32_bf16(kf, qf[kk], sacc[nf], 0, 0, 0);
        }
      }
      __builtin_amdgcn_s_setprio(0);

      // ---- mask + lane max + 2-shfl row max ----
      const bool full = (t0 + 64 <= q0);
      float mt = -1e30f;
#pragma unroll
      for (int nf = 0; nf < 4; ++nf) {
#pragma unroll
        for (int r = 0; r < 4; ++r) {
          float s = sacc[nf][r];
          if (!full) {
            const int tg = t0 + nf * 16 + hi * 4 + r;
            if (tg > qg) s = -1e30f;
          }
          sacc[nf][r] = s;
          mt = fmaxf(mt, s);
        }
      }
      mt = fmaxf(mt, __shfl_xor(mt, 16));
      mt = fmaxf(mt, __shfl_xor(mt, 32));
      const bool ok = (mt <= m_run + THR_LOG2);

      // ---- defer-max: rescale only when a row max grew (T13) ----
      if (!__all((int)ok)) {
        const float mn = fmaxf(m_run, mt);
        const float alpha = exp2_fast(m_run - mn);
        m_run = mn;
        l_lane *= alpha;
        const float a0 = __shfl(alpha, xbase + 0);
        const float a1 = __shfl(alpha, xbase + 1);
        const float a2 = __shfl(alpha, xbase + 2);
        const float a3 = __shfl(alpha, xbase + 3);
#pragma unroll
        for (int nf = 0; nf < 4; ++nf) {
          oacc[nf][0] *= a0; oacc[nf][1] *= a1;
          oacc[nf][2] *= a2; oacc[nf][3] *= a3;
        }
      }

      // ---- exp2 + packed P write (wave-private LDS) + lane-partial l ----
      {
        u16* lprow = lPw + lo * 72 + hi * 4;
        float ls = 0.f;
#pragma unroll
        for (int nf = 0; nf < 4; ++nf) {
          const float e0 = exp2_fast(sacc[nf][0] - m_run);
          const float e1 = exp2_fast(sacc[nf][1] - m_run);
          const float e2 = exp2_fast(sacc[nf][2] - m_run);
          const float e3 = exp2_fast(sacc[nf][3] - m_run);
          ls += (e0 + e1) + (e2 + e3);
          uint2 pk; pk.x = cvt_pk_bf16(e0, e1); pk.y = cvt_pk_bf16(e2, e3);
          *reinterpret_cast<uint2*>(lprow + nf * 16) = pk;
        }
        l_lane += ls;
      }

      // ---- O += P V  (V^T frags direct from global) ----
      __builtin_amdgcn_s_setprio(1);
#pragma unroll
      for (int kk = 0; kk < 2; ++kk) {
        bf16x8 pf = *reinterpret_cast<const bf16x8*>(&lPw[lo * 72 + kk * 32 + hi * 8]);
#pragma unroll
        for (int nf = 0; nf < 4; ++nf) {
          bf16x8 vf = *reinterpret_cast<const bf16x8*>(
              &Vb[(size_t)(nf * 16 + lo) * MROWS + t0 + kk * 32 + hi * 8]);
          oacc[nf] = __builtin_amdgcn_mfma_f32_16x16x32_bf16(pf, vf, oacc[nf], 0, 0, 0);
        }
      }
      __builtin_amdgcn_s_setprio(0);
    }

    // ---- epilogue: finish l across hi-group, redistribute, store ----
    {
      float ls = l_lane;
      ls += __shfl_xor(ls, 16);
      ls += __shfl_xor(ls, 32);
      const float inv = 1.f / ls;
      const float i0 = __shfl(inv, xbase + 0);
      const float i1 = __shfl(inv, xbase + 1);
      const float i2 = __shfl(inv, xbase + 2);
      const float i3 = __shfl(inv, xbase + 3);
#pragma unroll
      for (int nf = 0; nf < 4; ++nf) {
        const size_t rb0 = (size_t)(brow + q0w + hi * 4) * D_MODEL +
                           h * HD + nf * 16 + lo;
        Og[rb0 + 0 * D_MODEL] = f2bf(oacc[nf][0] * i0);
        Og[rb0 + 1 * D_MODEL] = f2bf(oacc[nf][1] * i1);
        Og[rb0 + 2 * D_MODEL] = f2bf(oacc[nf][2] * i2);
        Og[rb0 + 3 * D_MODEL] = f2bf(oacc[nf][3] * i3);
      }
    }
  }
}

// ---------------- launcher ----------------
extern "C" void kernel_launch(void* const* d_in, const int* in_sizes, int n_in,
                              void* d_out, int out_size, void* d_ws, size_t ws_size,
                              hipStream_t stream) {
  (void)in_sizes; (void)n_in; (void)out_size; (void)ws_size;
  const float* x  = (const float*)d_in[0];
  const float* wq = (const float*)d_in[1];
  const float* wk = (const float*)d_in[2];
  const float* wv = (const float*)d_in[3];
  const float* wo = (const float*)d_in[4];
  float* out = (float*)d_out;
  char* ws = (char*)d_ws;

  double* partials = (double*)ws;            // 640 * 8 B
  float* tabs = (float*)(ws + 6144);         // 40 floats
  size_t off = 8192;
  u16* xb    = (u16*)(ws + off); off += (size_t)MROWS * D_MODEL * 2;
  u16* wqkvs = (u16*)(ws + off); off += (size_t)NQKV * D_MODEL * 2;
  u16* wos   = (u16*)(ws + off); off += (size_t)D_MODEL * D_MODEL * 2;
  u16* qkvb  = (u16*)(ws + off); off += (size_t)MROWS * NQKV * 2;
  u16* ao    = (u16*)(ws + off); off += (size_t)MROWS * D_MODEL * 2;
  u16* vt    = (u16*)(ws + off); off += (size_t)512 * MROWS * 2;

  // 1. fused prep: weight signs + |w| partials + x->bf16
  prep_all<<<1152, 256, 0, stream>>>(wq, wk, wv, wo, x, wqkvs, wos, xb, partials);
  finalize_scales<<<1, 64, 0, stream>>>(partials, tabs);

  // 2. fused QKV projection; V columns stored transposed into vt
  gemm_bt<1, 1><<<dim3(NQKV / 128, MROWS / 128), 256, 0, stream>>>(
      xb, wqkvs, qkvb, tabs, vt, MROWS, NQKV, D_MODEL);

  // 3. GQA causal flash attention (barrier-free, 16 waves/CU)
  flash_attn<<<dim3(8, 64), 512, 0, stream>>>(qkvb, vt, ao);

  // 4. output projection (f32 out)
  gemm_bt<0, 0><<<dim3(D_MODEL / 128, MROWS / 128), 256, 0, stream>>>(
      ao, wos, out, tabs + 24, nullptr, MROWS, D_MODEL, D_MODEL);
}

// Round 8
// 202.225 us; speedup vs baseline: 1.9002x; 1.9002x over previous
//
#include <hip/hip_runtime.h>
#include <stdint.h>

// ---------------------------------------------------------------------------
// BitAttention round 8 (revert + additive):
//   - flash_attn v8 = round-6 v6 structure (paired q-tiles, dbuf LDS K/V^T,
//     swapped QK^T, defer-max, lazy l) + causal loop split (mask-free full
//     tiles) + tree max + XCD group pinning (each (b,kv) on one XCD's L2)
//   - round-7's zero-staging experiment REVERTED (latency-bound failure)
//   - gemm_bt VSPLIT -> vt[512][4096], Q pre-scaled by sm_scale*log2e (kept)
// ws layout (bytes):
//   [0,5120)    double partials[640]
//   [6144,6304) float tabs[40]
//   [8192,...)  xb(16M) wqkvs(12M) wos(8M) qkvb(24M) ao(16M) vt(4M)
// ---------------------------------------------------------------------------

#define D_MODEL 2048
#define S_LEN   2048
#define BATCH   2
#define NKV     8
#define HD      64
#define MROWS   (BATCH * S_LEN)   // 4096
#define NQKV    3072
#define LDQKV   3072

typedef unsigned short u16;
typedef __bf16 bf16x8 __attribute__((ext_vector_type(8)));
typedef float  f32x4  __attribute__((ext_vector_type(4)));

__device__ __forceinline__ u16 f2bf(float f) {
  union { float f; unsigned u; } v; v.f = f;
  unsigned r = v.u + 0x7FFFu + ((v.u >> 16) & 1u);   // RNE
  return (u16)(r >> 16);
}

__device__ __forceinline__ float exp2_fast(float x) {
  float r; asm("v_exp_f32 %0, %1" : "=v"(r) : "v"(x)); return r;
}

__device__ __forceinline__ unsigned cvt_pk_bf16(float a, float b) {
  unsigned r;
  asm("v_cvt_pk_bf16_f32 %0, %1, %2" : "=v"(r) : "v"(a), "v"(b));
  return r;
}

__device__ __forceinline__ void lds_load16(u16* lds, const u16* g) {
  __builtin_amdgcn_global_load_lds(
      (const __attribute__((address_space(1))) void*)g,
      (__attribute__((address_space(3))) void*)lds, 16, 0, 0);
}

#define SM_LOG2E 0.180336880f   // (1/sqrt(64)) * log2(e); folded into Q cols
#define THR_LOG2 11.5415603f    // 8 * log2(e)

// ---------------- fused prep: weight sign+|w| partials, x->bf16 ----------------
__global__ void prep_all(const float* __restrict__ wq, const float* __restrict__ wk,
                         const float* __restrict__ wv, const float* __restrict__ wo,
                         const float* __restrict__ x,
                         u16* __restrict__ wqkvs, u16* __restrict__ wos,
                         u16* __restrict__ xb, double* __restrict__ partials) {
  const int bid = blockIdx.x;
  const float* src; u16* dst; int n4, rb, nb; bool sgn = true;
  if (bid < 256)      { src = wq; dst = wqkvs;                  n4 = 1048576; rb = bid;       nb = 256; }
  else if (bid < 320) { src = wk; dst = wqkvs + 2048 * D_MODEL; n4 = 262144;  rb = bid - 256; nb = 64;  }
  else if (bid < 384) { src = wv; dst = wqkvs + 2560 * D_MODEL; n4 = 262144;  rb = bid - 320; nb = 64;  }
  else if (bid < 640) { src = wo; dst = wos;                    n4 = 1048576; rb = bid - 384; nb = 256; }
  else                { src = x;  dst = xb;                     n4 = 2097152; rb = bid - 640; nb = 512; sgn = false; }

  if (sgn) {
    double s = 0.0;
    for (int i = rb * 256 + threadIdx.x; i < n4; i += nb * 256) {
      float4 v = reinterpret_cast<const float4*>(src)[i];
      ushort4 o;
      o.x = v.x > 0.f ? 0x3F80 : (v.x < 0.f ? 0xBF80 : 0);
      o.y = v.y > 0.f ? 0x3F80 : (v.y < 0.f ? 0xBF80 : 0);
      o.z = v.z > 0.f ? 0x3F80 : (v.z < 0.f ? 0xBF80 : 0);
      o.w = v.w > 0.f ? 0x3F80 : (v.w < 0.f ? 0xBF80 : 0);
      reinterpret_cast<ushort4*>(dst)[i] = o;
      s += (double)fabsf(v.x) + (double)fabsf(v.y) +
           (double)fabsf(v.z) + (double)fabsf(v.w);
    }
    __shared__ double sm[256];
    sm[threadIdx.x] = s;
    __syncthreads();
    for (int off = 128; off > 0; off >>= 1) {
      if (threadIdx.x < off) sm[threadIdx.x] += sm[threadIdx.x + off];
      __syncthreads();
    }
    if (threadIdx.x == 0) partials[bid] = sm[0];
  } else {
    for (int i = rb * 256 + threadIdx.x; i < n4; i += nb * 256) {
      float4 v = reinterpret_cast<const float4*>(src)[i];
      ushort4 o;
      o.x = f2bf(v.x); o.y = f2bf(v.y); o.z = f2bf(v.z); o.w = f2bf(v.w);
      reinterpret_cast<ushort4*>(dst)[i] = o;
    }
  }
}

__global__ void finalize_scales(const double* __restrict__ partials,
                                float* __restrict__ tabs) {
  if (threadIdx.x == 0 && blockIdx.x == 0) {
    const int beg[4] = {0, 256, 320, 384};
    const int end[4] = {256, 320, 384, 640};
    const double counts[4] = {4194304.0, 1048576.0, 1048576.0, 4194304.0};
    float sc[4];
    for (int w = 0; w < 4; ++w) {
      double s = 0.0;
      for (int i = beg[w]; i < end[w]; ++i) s += partials[i];
      sc[w] = fmaxf((float)(s / counts[w]), 1e-5f);
    }
    for (int i = 0; i < 24; ++i)
      tabs[i] = (i < 16) ? sc[0] * SM_LOG2E : (i < 20 ? sc[1] : sc[2]);
    for (int i = 0; i < 16; ++i) tabs[24 + i] = sc[3];
  }
}

// ---------------- GEMM: C[m,n] = tab[bx] * sum_k A[m,k]*Bt[n,k] ----------------
// VSPLIT: blocks with bx>=20 (V columns) store TRANSPOSED into vt[512][4096].
template <int OUT_BF16, int VSPLIT>
__global__ __launch_bounds__(256, 2) void gemm_bt(
    const u16* __restrict__ A, const u16* __restrict__ Bt, void* __restrict__ Cv,
    const float* __restrict__ tab, u16* __restrict__ vt, int M, int N, int K) {
  __shared__ u16 lA[128 * 64];
  __shared__ u16 lB[128 * 64];
  const int tid = threadIdx.x;
  const int lane = tid & 63, wave = tid >> 6;
  const int lo = lane & 15, hi = lane >> 4;
  const int m0 = blockIdx.y * 128, n0 = blockIdx.x * 128;
  const int wr = (wave >> 1) * 64, wc = (wave & 1) * 64;

  f32x4 acc[4][4] = {};

  for (int k0 = 0; k0 < K; k0 += 64) {
#pragma unroll
    for (int it = 0; it < 4; ++it) {
      const int c = it * 256 + wave * 64 + lane;
      const int row = c >> 3, kc = (c & 7) << 3;
      lds_load16(&lA[(it * 256 + wave * 64) * 8], &A[(size_t)(m0 + row) * K + k0 + kc]);
      lds_load16(&lB[(it * 256 + wave * 64) * 8], &Bt[(size_t)(n0 + row) * K + k0 + kc]);
    }
    __syncthreads();
#pragma unroll
    for (int kk = 0; kk < 2; ++kk) {
      bf16x8 af[4], bfr[4];
#pragma unroll
      for (int i = 0; i < 4; ++i)
        af[i] = *reinterpret_cast<const bf16x8*>(&lA[(wr + i * 16 + lo) * 64 + kk * 32 + hi * 8]);
#pragma unroll
      for (int i = 0; i < 4; ++i)
        bfr[i] = *reinterpret_cast<const bf16x8*>(&lB[(wc + i * 16 + lo) * 64 + kk * 32 + hi * 8]);
#pragma unroll
      for (int mi = 0; mi < 4; ++mi)
#pragma unroll
        for (int ni = 0; ni < 4; ++ni)
          acc[mi][ni] = __builtin_amdgcn_mfma_f32_16x16x32_bf16(af[mi], bfr[ni], acc[mi][ni], 0, 0, 0);
    }
    __syncthreads();
  }

  const float scale = tab[blockIdx.x];
  if (VSPLIT && (int)blockIdx.x >= 20) {
    // V columns: transposed store, 4 consecutive rows (m) packed per dwordx2
#pragma unroll
    for (int mi = 0; mi < 4; ++mi) {
#pragma unroll
      for (int ni = 0; ni < 4; ++ni) {
        const int col = (n0 - 2560) + wc + ni * 16 + lo;       // 0..511
        const int row = m0 + wr + mi * 16 + hi * 4;            // mult of 4
        unsigned w01 = (unsigned)f2bf(acc[mi][ni][0] * scale) |
                       ((unsigned)f2bf(acc[mi][ni][1] * scale) << 16);
        unsigned w23 = (unsigned)f2bf(acc[mi][ni][2] * scale) |
                       ((unsigned)f2bf(acc[mi][ni][3] * scale) << 16);
        uint2 pk; pk.x = w01; pk.y = w23;
        *reinterpret_cast<uint2*>(vt + (size_t)col * MROWS + row) = pk;
      }
    }
    return;
  }
#pragma unroll
  for (int mi = 0; mi < 4; ++mi) {
#pragma unroll
    for (int ni = 0; ni < 4; ++ni) {
#pragma unroll
      for (int r = 0; r < 4; ++r) {
        const int row = m0 + wr + mi * 16 + hi * 4 + r;
        const int col = n0 + wc + ni * 16 + lo;
        const float v = acc[mi][ni][r] * scale;
        if (OUT_BF16)
          reinterpret_cast<u16*>(Cv)[(size_t)row * N + col] = f2bf(v);
        else
          reinterpret_cast<float*>(Cv)[(size_t)row * N + col] = v;
      }
    }
  }
}

// ---------------- flash attention v8 (GQA, causal, paired, split loops) --------
__device__ __forceinline__ void stage_tile(u16* dst, const u16* base, int ld,
                                           int tid, int wave) {
#pragma unroll
  for (int it = 0; it < 2; ++it) {
    const int c = it * 256 + tid;
    const int row = c >> 3;
    const int ch = (c & 7) ^ (row & 7);   // pre-swizzled source (rule #21)
    lds_load16(dst + (it * 256 + wave * 64) * 8, base + (size_t)row * ld + ch * 8);
  }
}

// One KV-tile step. MASKED=1 only for the 2 diagonal tiles.
#define TILE_BODY(MASKED)                                                      \
  {                                                                            \
    const int t0 = ti * 64;                                                    \
    const int cur = ti & 1;                                                    \
    u16* lKc = (u16*)lK[cur];                                                  \
    u16* lVc = (u16*)lV[cur];                                                  \
    f32x4 sacc[2][4] = {};                                                     \
    __builtin_amdgcn_s_setprio(1);                                             \
    _Pragma("unroll")                                                          \
    for (int kk = 0; kk < 2; ++kk) {                                           \
      _Pragma("unroll")                                                        \
      for (int nf = 0; nf < 4; ++nf) {                                         \
        bf16x8 kf = *reinterpret_cast<const bf16x8*>(                          \
            &lKc[(nf * 16 + lo) * 64 + ((kk * 32 + hi * 8) ^ swl)]);           \
        _Pragma("unroll")                                                      \
        for (int mi = 0; mi < 2; ++mi)                                         \
          sacc[mi][nf] = __builtin_amdgcn_mfma_f32_16x16x32_bf16(              \
              kf, qf[mi][kk], sacc[mi][nf], 0, 0, 0);                          \
      }                                                                        \
    }                                                                          \
    __builtin_amdgcn_s_setprio(0);                                             \
    const bool has_next = (ti + 1 < nt);                                       \
    if (has_next) {                                                            \
      stage_tile(lK[cur ^ 1], Kb + (size_t)(brow + t0 + 64) * LDQKV, LDQKV,    \
                 tid, wave);                                                   \
      stage_tile(lV[cur ^ 1], Vb + t0 + 64, MROWS, tid, wave);                 \
    }                                                                          \
    float rowmax[2];                                                           \
    bool ok = true;                                                            \
    _Pragma("unroll")                                                          \
    for (int mi = 0; mi < 2; ++mi) {                                           \
      if (MASKED) {                                                            \
        const int qg = q0w + mi * 16 + lo;                                     \
        _Pragma("unroll")                                                      \
        for (int nf = 0; nf < 4; ++nf) {                                       \
          _Pragma("unroll")                                                    \
          for (int r = 0; r < 4; ++r) {                                        \
            const int tg = t0 + nf * 16 + hi * 4 + r;                          \
            if (tg > qg) sacc[mi][nf][r] = -1e30f;                             \
          }                                                                    \
        }                                                                      \
      }                                                                        \
      float mnf[4];                                                            \
      _Pragma("unroll")                                                        \
      for (int nf = 0; nf < 4; ++nf)                                           \
        mnf[nf] = fmaxf(fmaxf(sacc[mi][nf][0], sacc[mi][nf][1]),               \
                        fmaxf(sacc[mi][nf][2], sacc[mi][nf][3]));              \
      float mt = fmaxf(fmaxf(mnf[0], mnf[1]), fmaxf(mnf[2], mnf[3]));          \
      mt = fmaxf(mt, __shfl_xor(mt, 16));                                      \
      mt = fmaxf(mt, __shfl_xor(mt, 32));                                      \
      rowmax[mi] = mt;                                                         \
      ok = ok && (mt <= m_run[mi] + THR_LOG2);                                 \
    }                                                                          \
    if (!__all((int)ok)) {                                                     \
      _Pragma("unroll")                                                        \
      for (int mi = 0; mi < 2; ++mi) {                                         \
        const float mn = fmaxf(m_run[mi], rowmax[mi]);                         \
        const float alpha = exp2_fast(m_run[mi] - mn);                         \
        m_run[mi] = mn;                                                        \
        l_lane[mi] *= alpha;                                                   \
        const float a0 = __shfl(alpha, xbase + 0);                             \
        const float a1 = __shfl(alpha, xbase + 1);                             \
        const float a2 = __shfl(alpha, xbase + 2);                             \
        const float a3 = __shfl(alpha, xbase + 3);                             \
        _Pragma("unroll")                                                      \
        for (int nf = 0; nf < 4; ++nf) {                                       \
          oacc[mi][nf][0] *= a0; oacc[mi][nf][1] *= a1;                        \
          oacc[mi][nf][2] *= a2; oacc[mi][nf][3] *= a3;                        \
        }                                                                      \
      }                                                                        \
    }                                                                          \
    _Pragma("unroll")                                                          \
    for (int mi = 0; mi < 2; ++mi) {                                           \
      u16* lprow = &lP[wave][(mi * 16 + lo) * 72 + hi * 4];                    \
      float ls = 0.f;                                                          \
      _Pragma("unroll")                                                        \
      for (int nf = 0; nf < 4; ++nf) {                                         \
        const float e0 = exp2_fast(sacc[mi][nf][0] - m_run[mi]);               \
        const float e1 = exp2_fast(sacc[mi][nf][1] - m_run[mi]);               \
        const float e2 = exp2_fast(sacc[mi][nf][2] - m_run[mi]);               \
        const float e3 = exp2_fast(sacc[mi][nf][3] - m_run[mi]);               \
        ls += (e0 + e1) + (e2 + e3);                                           \
        uint2 pk; pk.x = cvt_pk_bf16(e0, e1); pk.y = cvt_pk_bf16(e2, e3);      \
        *reinterpret_cast<uint2*>(lprow + nf * 16) = pk;                       \
      }                                                                        \
      l_lane[mi] += ls;                                                        \
    }                                                                          \
    __builtin_amdgcn_s_setprio(1);                                             \
    _Pragma("unroll")                                                          \
    for (int kk = 0; kk < 2; ++kk) {                                           \
      bf16x8 pf[2];                                                            \
      _Pragma("unroll")                                                        \
      for (int mi = 0; mi < 2; ++mi)                                           \
        pf[mi] = *reinterpret_cast<const bf16x8*>(                             \
            &lP[wave][(mi * 16 + lo) * 72 + kk * 32 + hi * 8]);                \
      _Pragma("unroll")                                                        \
      for (int nf = 0; nf < 4; ++nf) {                                         \
        bf16x8 vf = *reinterpret_cast<const bf16x8*>(                          \
            &lVc[(nf * 16 + lo) * 64 + ((kk * 32 + hi * 8) ^ swl)]);           \
        _Pragma("unroll")                                                      \
        for (int mi = 0; mi < 2; ++mi)                                         \
          oacc[mi][nf] = __builtin_amdgcn_mfma_f32_16x16x32_bf16(              \
              pf[mi], vf, oacc[mi][nf], 0, 0, 0);                              \
      }                                                                        \
    }                                                                          \
    __builtin_amdgcn_s_setprio(0);                                             \
    __syncthreads();                                                           \
  }

__global__ __launch_bounds__(256, 2) void flash_attn(
    const u16* __restrict__ QKV, const u16* __restrict__ VT,
    u16* __restrict__ Og) {
  __shared__ u16 lK[2][64 * 64];    // [t][d], XOR-swizzled chunks
  __shared__ u16 lV[2][64 * 64];    // [d][t], XOR-swizzled chunks
  __shared__ u16 lP[4][32 * 72];    // per-wave P[q][t], stride 72

  const int tid = threadIdx.x;
  const int lane = tid & 63, wave = tid >> 6;
  const int lo = lane & 15, hi = lane >> 4;
  // XCD group pinning: linear id mod 8 ~ XCD; give each (b,kv) group's 32
  // blocks one residue class -> K/V^T (512KB/group, 2 groups/XCD) L2-resident.
  const int lin = (int)blockIdx.y * 8 + (int)blockIdx.x;   // 0..511
  const int xcd = lin & 7, slot = lin >> 3;
  const int G = xcd * 2 + (slot >> 5);    // 0..15 = (b, kv)
  const int wb = slot & 31;               // 0..31 = (g_h, lbx)
  const int b = G >> 3, kv = G & 7;
  const int h = kv * 4 + (wb >> 3);
  const int lbx = wb & 7;
  const int brow = b * S_LEN;
  const u16* Q  = QKV + h * HD;
  const u16* Kb = QKV + 2048 + kv * HD;                   // row stride LDQKV
  const u16* Vb = VT + (size_t)(kv * HD) * MROWS + brow;  // row d, stride MROWS
  const int swl = (lo & 7) << 3;
  const int xbase = (lane & 48) | ((lane >> 2) & 12);     // lane with lo=hi*4(+r)

#pragma unroll 1
  for (int pi = 0; pi < 2; ++pi) {
    const int qt = pi == 0 ? lbx : (15 - lbx);
    const int q0 = qt * 128;
    const int q0w = q0 + wave * 32;
    const int nt = 2 * qt + 2;

    // Q fragments resident for the pass (pre-scaled by sm_scale*log2e)
    bf16x8 qf[2][2];
#pragma unroll
    for (int mi = 0; mi < 2; ++mi) {
      const size_t qr = (size_t)(brow + q0w + mi * 16 + lo) * LDQKV;
#pragma unroll
      for (int kk = 0; kk < 2; ++kk)
        qf[mi][kk] = *reinterpret_cast<const bf16x8*>(&Q[qr + kk * 32 + hi * 8]);
    }

    f32x4 oacc[2][4] = {};
    float m_run[2] = {-1e30f, -1e30f};
    float l_lane[2] = {0.f, 0.f};

    // prologue: stage tile 0 into buffer 0
    stage_tile(lK[0], Kb + (size_t)brow * LDQKV, LDQKV, tid, wave);
    stage_tile(lV[0], Vb, MROWS, tid, wave);
    __syncthreads();

    // full tiles: no causal masking needed (t0+64 <= q0)
#pragma unroll 1
    for (int ti = 0; ti < 2 * qt; ++ti) TILE_BODY(0)
    // diagonal tiles (2): per-element masking
#pragma unroll 1
    for (int ti = 2 * qt; ti < nt; ++ti) TILE_BODY(1)

    // ---- epilogue: finish l across hi-group, redistribute, store ----
#pragma unroll
    for (int mi = 0; mi < 2; ++mi) {
      float ls = l_lane[mi];
      ls += __shfl_xor(ls, 16);
      ls += __shfl_xor(ls, 32);
      const float inv = 1.f / ls;
      const float i0 = __shfl(inv, xbase + 0);
      const float i1 = __shfl(inv, xbase + 1);
      const float i2 = __shfl(inv, xbase + 2);
      const float i3 = __shfl(inv, xbase + 3);
#pragma unroll
      for (int nf = 0; nf < 4; ++nf) {
        const size_t rb0 = (size_t)(brow + q0w + mi * 16 + hi * 4) * D_MODEL +
                           h * HD + nf * 16 + lo;
        Og[rb0 + 0 * D_MODEL] = f2bf(oacc[mi][nf][0] * i0);
        Og[rb0 + 1 * D_MODEL] = f2bf(oacc[mi][nf][1] * i1);
        Og[rb0 + 2 * D_MODEL] = f2bf(oacc[mi][nf][2] * i2);
        Og[rb0 + 3 * D_MODEL] = f2bf(oacc[mi][nf][3] * i3);
      }
    }
  }
}

// ---------------- launcher ----------------
extern "C" void kernel_launch(void* const* d_in, const int* in_sizes, int n_in,
                              void* d_out, int out_size, void* d_ws, size_t ws_size,
                              hipStream_t stream) {
  (void)in_sizes; (void)n_in; (void)out_size; (void)ws_size;
  const float* x  = (const float*)d_in[0];
  const float* wq = (const float*)d_in[1];
  const float* wk = (const float*)d_in[2];
  const float* wv = (const float*)d_in[3];
  const float* wo = (const float*)d_in[4];
  float* out = (float*)d_out;
  char* ws = (char*)d_ws;

  double* partials = (double*)ws;            // 640 * 8 B
  float* tabs = (float*)(ws + 6144);         // 40 floats
  size_t off = 8192;
  u16* xb    = (u16*)(ws + off); off += (size_t)MROWS * D_MODEL * 2;
  u16* wqkvs = (u16*)(ws + off); off += (size_t)NQKV * D_MODEL * 2;
  u16* wos   = (u16*)(ws + off); off += (size_t)D_MODEL * D_MODEL * 2;
  u16* qkvb  = (u16*)(ws + off); off += (size_t)MROWS * NQKV * 2;
  u16* ao    = (u16*)(ws + off); off += (size_t)MROWS * D_MODEL * 2;
  u16* vt    = (u16*)(ws + off); off += (size_t)512 * MROWS * 2;

  // 1. fused prep: weight signs + |w| partials + x->bf16
  prep_all<<<1152, 256, 0, stream>>>(wq, wk, wv, wo, x, wqkvs, wos, xb, partials);
  finalize_scales<<<1, 64, 0, stream>>>(partials, tabs);

  // 2. fused QKV projection; V columns stored transposed into vt
  gemm_bt<1, 1><<<dim3(NQKV / 128, MROWS / 128), 256, 0, stream>>>(
      xb, wqkvs, qkvb, tabs, vt, MROWS, NQKV, D_MODEL);

  // 3. GQA causal flash attention (paired, XCD-pinned, split loops)
  flash_attn<<<dim3(8, 64), 256, 0, stream>>>(qkvb, vt, ao);

  // 4. output projection (f32 out)
  gemm_bt<0, 0><<<dim3(D_MODEL / 128, MROWS / 128), 256, 0, stream>>>(
      ao, wos, out, tabs + 24, nullptr, MROWS, D_MODEL, D_MODEL);
}

// Round 9
// 199.464 us; speedup vs baseline: 1.9265x; 1.0138x over previous
//
#include <hip/hip_runtime.h>
#include <stdint.h>

// ---------------------------------------------------------------------------
// BitAttention round 8 (revert + additive):
//   - flash_attn v8 = round-6 v6 structure (paired q-tiles, dbuf LDS K/V^T,
//     swapped QK^T, defer-max, lazy l) + causal loop split (mask-free full
//     tiles) + tree max + XCD group pinning (each (b,kv) on one XCD's L2)
//   - round-7's zero-staging experiment REVERTED (latency-bound failure)
//   - gemm_bt VSPLIT -> vt[512][4096], Q pre-scaled by sm_scale*log2e (kept)
// ws layout (bytes):
//   [0,5120)    double partials[640]
//   [6144,6304) float tabs[40]
//   [8192,...)  xb(16M) wqkvs(12M) wos(8M) qkvb(24M) ao(16M) vt(4M)
// ---------------------------------------------------------------------------

#define D_MODEL 2048
#define S_LEN   2048
#define BATCH   2
#define NKV     8
#define HD      64
#define MROWS   (BATCH * S_LEN)   // 4096
#define NQKV    3072
#define LDQKV   3072

typedef unsigned short u16;
typedef __bf16 bf16x8 __attribute__((ext_vector_type(8)));
typedef float  f32x4  __attribute__((ext_vector_type(4)));

__device__ __forceinline__ u16 f2bf(float f) {
  union { float f; unsigned u; } v; v.f = f;
  unsigned r = v.u + 0x7FFFu + ((v.u >> 16) & 1u);   // RNE
  return (u16)(r >> 16);
}

__device__ __forceinline__ float exp2_fast(float x) {
  float r; asm("v_exp_f32 %0, %1" : "=v"(r) : "v"(x)); return r;
}

__device__ __forceinline__ unsigned cvt_pk_bf16(float a, float b) {
  unsigned r;
  asm("v_cvt_pk_bf16_f32 %0, %1, %2" : "=v"(r) : "v"(a), "v"(b));
  return r;
}

__device__ __forceinline__ void lds_load16(u16* lds, const u16* g) {
  __builtin_amdgcn_global_load_lds(
      (const __attribute__((address_space(1))) void*)g,
      (__attribute__((address_space(3))) void*)lds, 16, 0, 0);
}

#define SM_LOG2E 0.180336880f   // (1/sqrt(64)) * log2(e); folded into Q cols
#define THR_LOG2 11.5415603f    // 8 * log2(e)

// ---------------- fused prep: weight sign+|w| partials, x->bf16 ----------------
__global__ void prep_all(const float* __restrict__ wq, const float* __restrict__ wk,
                         const float* __restrict__ wv, const float* __restrict__ wo,
                         const float* __restrict__ x,
                         u16* __restrict__ wqkvs, u16* __restrict__ wos,
                         u16* __restrict__ xb, double* __restrict__ partials) {
  const int bid = blockIdx.x;
  const float* src; u16* dst; int n4, rb, nb; bool sgn = true;
  if (bid < 256)      { src = wq; dst = wqkvs;                  n4 = 1048576; rb = bid;       nb = 256; }
  else if (bid < 320) { src = wk; dst = wqkvs + 2048 * D_MODEL; n4 = 262144;  rb = bid - 256; nb = 64;  }
  else if (bid < 384) { src = wv; dst = wqkvs + 2560 * D_MODEL; n4 = 262144;  rb = bid - 320; nb = 64;  }
  else if (bid < 640) { src = wo; dst = wos;                    n4 = 1048576; rb = bid - 384; nb = 256; }
  else                { src = x;  dst = xb;                     n4 = 2097152; rb = bid - 640; nb = 512; sgn = false; }

  if (sgn) {
    double s = 0.0;
    for (int i = rb * 256 + threadIdx.x; i < n4; i += nb * 256) {
      float4 v = reinterpret_cast<const float4*>(src)[i];
      ushort4 o;
      o.x = v.x > 0.f ? 0x3F80 : (v.x < 0.f ? 0xBF80 : 0);
      o.y = v.y > 0.f ? 0x3F80 : (v.y < 0.f ? 0xBF80 : 0);
      o.z = v.z > 0.f ? 0x3F80 : (v.z < 0.f ? 0xBF80 : 0);
      o.w = v.w > 0.f ? 0x3F80 : (v.w < 0.f ? 0xBF80 : 0);
      reinterpret_cast<ushort4*>(dst)[i] = o;
      s += (double)fabsf(v.x) + (double)fabsf(v.y) +
           (double)fabsf(v.z) + (double)fabsf(v.w);
    }
    __shared__ double sm[256];
    sm[threadIdx.x] = s;
    __syncthreads();
    for (int off = 128; off > 0; off >>= 1) {
      if (threadIdx.x < off) sm[threadIdx.x] += sm[threadIdx.x + off];
      __syncthreads();
    }
    if (threadIdx.x == 0) partials[bid] = sm[0];
  } else {
    for (int i = rb * 256 + threadIdx.x; i < n4; i += nb * 256) {
      float4 v = reinterpret_cast<const float4*>(src)[i];
      ushort4 o;
      o.x = f2bf(v.x); o.y = f2bf(v.y); o.z = f2bf(v.z); o.w = f2bf(v.w);
      reinterpret_cast<ushort4*>(dst)[i] = o;
    }
  }
}

__global__ void finalize_scales(const double* __restrict__ partials,
                                float* __restrict__ tabs) {
  if (threadIdx.x == 0 && blockIdx.x == 0) {
    const int beg[4] = {0, 256, 320, 384};
    const int end[4] = {256, 320, 384, 640};
    const double counts[4] = {4194304.0, 1048576.0, 1048576.0, 4194304.0};
    float sc[4];
    for (int w = 0; w < 4; ++w) {
      double s = 0.0;
      for (int i = beg[w]; i < end[w]; ++i) s += partials[i];
      sc[w] = fmaxf((float)(s / counts[w]), 1e-5f);
    }
    for (int i = 0; i < 24; ++i)
      tabs[i] = (i < 16) ? sc[0] * SM_LOG2E : (i < 20 ? sc[1] : sc[2]);
    for (int i = 0; i < 16; ++i) tabs[24 + i] = sc[3];
  }
}

// ---------------- GEMM: C[m,n] = tab[bx] * sum_k A[m,k]*Bt[n,k] ----------------
// VSPLIT: blocks with bx>=20 (V columns) store TRANSPOSED into vt[512][4096].
template <int OUT_BF16, int VSPLIT>
__global__ __launch_bounds__(256, 2) void gemm_bt(
    const u16* __restrict__ A, const u16* __restrict__ Bt, void* __restrict__ Cv,
    const float* __restrict__ tab, u16* __restrict__ vt, int M, int N, int K) {
  __shared__ u16 lA[128 * 64];
  __shared__ u16 lB[128 * 64];
  const int tid = threadIdx.x;
  const int lane = tid & 63, wave = tid >> 6;
  const int lo = lane & 15, hi = lane >> 4;
  const int m0 = blockIdx.y * 128, n0 = blockIdx.x * 128;
  const int wr = (wave >> 1) * 64, wc = (wave & 1) * 64;

  f32x4 acc[4][4] = {};

  for (int k0 = 0; k0 < K; k0 += 64) {
#pragma unroll
    for (int it = 0; it < 4; ++it) {
      const int c = it * 256 + wave * 64 + lane;
      const int row = c >> 3, kc = (c & 7) << 3;
      lds_load16(&lA[(it * 256 + wave * 64) * 8], &A[(size_t)(m0 + row) * K + k0 + kc]);
      lds_load16(&lB[(it * 256 + wave * 64) * 8], &Bt[(size_t)(n0 + row) * K + k0 + kc]);
    }
    __syncthreads();
#pragma unroll
    for (int kk = 0; kk < 2; ++kk) {
      bf16x8 af[4], bfr[4];
#pragma unroll
      for (int i = 0; i < 4; ++i)
        af[i] = *reinterpret_cast<const bf16x8*>(&lA[(wr + i * 16 + lo) * 64 + kk * 32 + hi * 8]);
#pragma unroll
      for (int i = 0; i < 4; ++i)
        bfr[i] = *reinterpret_cast<const bf16x8*>(&lB[(wc + i * 16 + lo) * 64 + kk * 32 + hi * 8]);
#pragma unroll
      for (int mi = 0; mi < 4; ++mi)
#pragma unroll
        for (int ni = 0; ni < 4; ++ni)
          acc[mi][ni] = __builtin_amdgcn_mfma_f32_16x16x32_bf16(af[mi], bfr[ni], acc[mi][ni], 0, 0, 0);
    }
    __syncthreads();
  }

  const float scale = tab[blockIdx.x];
  if (VSPLIT && (int)blockIdx.x >= 20) {
    // V columns: transposed store, 4 consecutive rows (m) packed per dwordx2
#pragma unroll
    for (int mi = 0; mi < 4; ++mi) {
#pragma unroll
      for (int ni = 0; ni < 4; ++ni) {
        const int col = (n0 - 2560) + wc + ni * 16 + lo;       // 0..511
        const int row = m0 + wr + mi * 16 + hi * 4;            // mult of 4
        unsigned w01 = (unsigned)f2bf(acc[mi][ni][0] * scale) |
                       ((unsigned)f2bf(acc[mi][ni][1] * scale) << 16);
        unsigned w23 = (unsigned)f2bf(acc[mi][ni][2] * scale) |
                       ((unsigned)f2bf(acc[mi][ni][3] * scale) << 16);
        uint2 pk; pk.x = w01; pk.y = w23;
        *reinterpret_cast<uint2*>(vt + (size_t)col * MROWS + row) = pk;
      }
    }
    return;
  }
#pragma unroll
  for (int mi = 0; mi < 4; ++mi) {
#pragma unroll
    for (int ni = 0; ni < 4; ++ni) {
#pragma unroll
      for (int r = 0; r < 4; ++r) {
        const int row = m0 + wr + mi * 16 + hi * 4 + r;
        const int col = n0 + wc + ni * 16 + lo;
        const float v = acc[mi][ni][r] * scale;
        if (OUT_BF16)
          reinterpret_cast<u16*>(Cv)[(size_t)row * N + col] = f2bf(v);
        else
          reinterpret_cast<float*>(Cv)[(size_t)row * N + col] = v;
      }
    }
  }
}

// ---------------- flash attention v8 (GQA, causal, paired, split loops) --------
__device__ __forceinline__ void stage_tile(u16* dst, const u16* base, int ld,
                                           int tid, int wave) {
#pragma unroll
  for (int it = 0; it < 2; ++it) {
    const int c = it * 256 + tid;
    const int row = c >> 3;
    const int ch = (c & 7) ^ (row & 7);   // pre-swizzled source (rule #21)
    lds_load16(dst + (it * 256 + wave * 64) * 8, base + (size_t)row * ld + ch * 8);
  }
}

// One KV-tile step. MASKED=1 only for the 2 diagonal tiles.
#define TILE_BODY(MASKED)                                                      \
  {                                                                            \
    const int t0 = ti * 64;                                                    \
    const int cur = ti & 1;                                                    \
    u16* lKc = (u16*)lK[cur];                                                  \
    u16* lVc = (u16*)lV[cur];                                                  \
    f32x4 sacc[2][4] = {};                                                     \
    __builtin_amdgcn_s_setprio(1);                                             \
    _Pragma("unroll")                                                          \
    for (int kk = 0; kk < 2; ++kk) {                                           \
      _Pragma("unroll")                                                        \
      for (int nf = 0; nf < 4; ++nf) {                                         \
        bf16x8 kf = *reinterpret_cast<const bf16x8*>(                          \
            &lKc[(nf * 16 + lo) * 64 + ((kk * 32 + hi * 8) ^ swl)]);           \
        _Pragma("unroll")                                                      \
        for (int mi = 0; mi < 2; ++mi)                                         \
          sacc[mi][nf] = __builtin_amdgcn_mfma_f32_16x16x32_bf16(              \
              kf, qf[mi][kk], sacc[mi][nf], 0, 0, 0);                          \
      }                                                                        \
    }                                                                          \
    __builtin_amdgcn_s_setprio(0);                                             \
    const bool has_next = (ti + 1 < nt);                                       \
    if (has_next) {                                                            \
      stage_tile(lK[cur ^ 1], Kb + (size_t)(brow + t0 + 64) * LDQKV, LDQKV,    \
                 tid, wave);                                                   \
      stage_tile(lV[cur ^ 1], Vb + t0 + 64, MROWS, tid, wave);                 \
    }                                                                          \
    float rowmax[2];                                                           \
    bool ok = true;                                                            \
    _Pragma("unroll")                                                          \
    for (int mi = 0; mi < 2; ++mi) {                                           \
      if (MASKED) {                                                            \
        const int qg = q0w + mi * 16 + lo;                                     \
        _Pragma("unroll")                                                      \
        for (int nf = 0; nf < 4; ++nf) {                                       \
          _Pragma("unroll")                                                    \
          for (int r = 0; r < 4; ++r) {                                        \
            const int tg = t0 + nf * 16 + hi * 4 + r;                          \
            if (tg > qg) sacc[mi][nf][r] = -1e30f;                             \
          }                                                                    \
        }                                                                      \
      }                                                                        \
      float mnf[4];                                                            \
      _Pragma("unroll")                                                        \
      for (int nf = 0; nf < 4; ++nf)                                           \
        mnf[nf] = fmaxf(fmaxf(sacc[mi][nf][0], sacc[mi][nf][1]),               \
                        fmaxf(sacc[mi][nf][2], sacc[mi][nf][3]));              \
      float mt = fmaxf(fmaxf(mnf[0], mnf[1]), fmaxf(mnf[2], mnf[3]));          \
      mt = fmaxf(mt, __shfl_xor(mt, 16));                                      \
      mt = fmaxf(mt, __shfl_xor(mt, 32));                                      \
      rowmax[mi] = mt;                                                         \
      ok = ok && (mt <= m_run[mi] + THR_LOG2);                                 \
    }                                                                          \
    if (!__all((int)ok)) {                                                     \
      _Pragma("unroll")                                                        \
      for (int mi = 0; mi < 2; ++mi) {                                         \
        const float mn = fmaxf(m_run[mi], rowmax[mi]);                         \
        const float alpha = exp2_fast(m_run[mi] - mn);                         \
        m_run[mi] = mn;                                                        \
        l_lane[mi] *= alpha;                                                   \
        const float a0 = __shfl(alpha, xbase + 0);                             \
        const float a1 = __shfl(alpha, xbase + 1);                             \
        const float a2 = __shfl(alpha, xbase + 2);                             \
        const float a3 = __shfl(alpha, xbase + 3);                             \
        _Pragma("unroll")                                                      \
        for (int nf = 0; nf < 4; ++nf) {                                       \
          oacc[mi][nf][0] *= a0; oacc[mi][nf][1] *= a1;                        \
          oacc[mi][nf][2] *= a2; oacc[mi][nf][3] *= a3;                        \
        }                                                                      \
      }                                                                        \
    }                                                                          \
    _Pragma("unroll")                                                          \
    for (int mi = 0; mi < 2; ++mi) {                                           \
      u16* lprow = &lP[wave][(mi * 16 + lo) * 72 + hi * 4];                    \
      float ls = 0.f;                                                          \
      _Pragma("unroll")                                                        \
      for (int nf = 0; nf < 4; ++nf) {                                         \
        const float e0 = exp2_fast(sacc[mi][nf][0] - m_run[mi]);               \
        const float e1 = exp2_fast(sacc[mi][nf][1] - m_run[mi]);               \
        const float e2 = exp2_fast(sacc[mi][nf][2] - m_run[mi]);               \
        const float e3 = exp2_fast(sacc[mi][nf][3] - m_run[mi]);               \
        ls += (e0 + e1) + (e2 + e3);                                           \
        uint2 pk; pk.x = cvt_pk_bf16(e0, e1); pk.y = cvt_pk_bf16(e2, e3);      \
        *reinterpret_cast<uint2*>(lprow + nf * 16) = pk;                       \
      }                                                                        \
      l_lane[mi] += ls;                                                        \
    }                                                                          \
    __builtin_amdgcn_s_setprio(1);                                             \
    _Pragma("unroll")                                                          \
    for (int kk = 0; kk < 2; ++kk) {                                           \
      bf16x8 pf[2];                                                            \
      _Pragma("unroll")                                                        \
      for (int mi = 0; mi < 2; ++mi)                                           \
        pf[mi] = *reinterpret_cast<const bf16x8*>(                             \
            &lP[wave][(mi * 16 + lo) * 72 + kk * 32 + hi * 8]);                \
      _Pragma("unroll")                                                        \
      for (int nf = 0; nf < 4; ++nf) {                                         \
        bf16x8 vf = *reinterpret_cast<const bf16x8*>(                          \
            &lVc[(nf * 16 + lo) * 64 + ((kk * 32 + hi * 8) ^ swl)]);           \
        _Pragma("unroll")                                                      \
        for (int mi = 0; mi < 2; ++mi)                                         \
          oacc[mi][nf] = __builtin_amdgcn_mfma_f32_16x16x32_bf16(              \
              pf[mi], vf, oacc[mi][nf], 0, 0, 0);                              \
      }                                                                        \
    }                                                                          \
    __builtin_amdgcn_s_setprio(0);                                             \
    __syncthreads();                                                           \
  }

__global__ __launch_bounds__(256, 2) void flash_attn(
    const u16* __restrict__ QKV, const u16* __restrict__ VT,
    u16* __restrict__ Og) {
  __shared__ u16 lK[2][64 * 64];    // [t][d], XOR-swizzled chunks
  __shared__ u16 lV[2][64 * 64];    // [d][t], XOR-swizzled chunks
  __shared__ u16 lP[4][32 * 72];    // per-wave P[q][t], stride 72

  const int tid = threadIdx.x;
  const int lane = tid & 63, wave = tid >> 6;
  const int lo = lane & 15, hi = lane >> 4;
  // XCD group pinning: linear id mod 8 ~ XCD; give each (b,kv) group's 32
  // blocks one residue class -> K/V^T (512KB/group, 2 groups/XCD) L2-resident.
  const int lin = (int)blockIdx.y * 8 + (int)blockIdx.x;   // 0..511
  const int xcd = lin & 7, slot = lin >> 3;
  const int G = xcd * 2 + (slot >> 5);    // 0..15 = (b, kv)
  const int wb = slot & 31;               // 0..31 = (g_h, lbx)
  const int b = G >> 3, kv = G & 7;
  const int h = kv * 4 + (wb >> 3);
  const int lbx = wb & 7;
  const int brow = b * S_LEN;
  const u16* Q  = QKV + h * HD;
  const u16* Kb = QKV + 2048 + kv * HD;                   // row stride LDQKV
  const u16* Vb = VT + (size_t)(kv * HD) * MROWS + brow;  // row d, stride MROWS
  const int swl = (lo & 7) << 3;
  const int xbase = (lane & 48) | ((lane >> 2) & 12);     // lane with lo=hi*4(+r)

#pragma unroll 1
  for (int pi = 0; pi < 2; ++pi) {
    const int qt = pi == 0 ? lbx : (15 - lbx);
    const int q0 = qt * 128;
    const int q0w = q0 + wave * 32;
    const int nt = 2 * qt + 2;

    // Q fragments resident for the pass (pre-scaled by sm_scale*log2e)
    bf16x8 qf[2][2];
#pragma unroll
    for (int mi = 0; mi < 2; ++mi) {
      const size_t qr = (size_t)(brow + q0w + mi * 16 + lo) * LDQKV;
#pragma unroll
      for (int kk = 0; kk < 2; ++kk)
        qf[mi][kk] = *reinterpret_cast<const bf16x8*>(&Q[qr + kk * 32 + hi * 8]);
    }

    f32x4 oacc[2][4] = {};
    float m_run[2] = {-1e30f, -1e30f};
    float l_lane[2] = {0.f, 0.f};

    // prologue: stage tile 0 into buffer 0
    stage_tile(lK[0], Kb + (size_t)brow * LDQKV, LDQKV, tid, wave);
    stage_tile(lV[0], Vb, MROWS, tid, wave);
    __syncthreads();

    // full tiles: no causal masking needed (t0+64 <= q0)
#pragma unroll 1
    for (int ti = 0; ti < 2 * qt; ++ti) TILE_BODY(0)
    // diagonal tiles (2): per-element masking
#pragma unroll 1
    for (int ti = 2 * qt; ti < nt; ++ti) TILE_BODY(1)

    // ---- epilogue: finish l across hi-group, redistribute, store ----
#pragma unroll
    for (int mi = 0; mi < 2; ++mi) {
      float ls = l_lane[mi];
      ls += __shfl_xor(ls, 16);
      ls += __shfl_xor(ls, 32);
      const float inv = 1.f / ls;
      const float i0 = __shfl(inv, xbase + 0);
      const float i1 = __shfl(inv, xbase + 1);
      const float i2 = __shfl(inv, xbase + 2);
      const float i3 = __shfl(inv, xbase + 3);
#pragma unroll
      for (int nf = 0; nf < 4; ++nf) {
        const size_t rb0 = (size_t)(brow + q0w + mi * 16 + hi * 4) * D_MODEL +
                           h * HD + nf * 16 + lo;
        Og[rb0 + 0 * D_MODEL] = f2bf(oacc[mi][nf][0] * i0);
        Og[rb0 + 1 * D_MODEL] = f2bf(oacc[mi][nf][1] * i1);
        Og[rb0 + 2 * D_MODEL] = f2bf(oacc[mi][nf][2] * i2);
        Og[rb0 + 3 * D_MODEL] = f2bf(oacc[mi][nf][3] * i3);
      }
    }
  }
}

// ---------------- launcher ----------------
extern "C" void kernel_launch(void* const* d_in, const int* in_sizes, int n_in,
                              void* d_out, int out_size, void* d_ws, size_t ws_size,
                              hipStream_t stream) {
  (void)in_sizes; (void)n_in; (void)out_size; (void)ws_size;
  const float* x  = (const float*)d_in[0];
  const float* wq = (const float*)d_in[1];
  const float* wk = (const float*)d_in[2];
  const float* wv = (const float*)d_in[3];
  const float* wo = (const float*)d_in[4];
  float* out = (float*)d_out;
  char* ws = (char*)d_ws;

  double* partials = (double*)ws;            // 640 * 8 B
  float* tabs = (float*)(ws + 6144);         // 40 floats
  size_t off = 8192;
  u16* xb    = (u16*)(ws + off); off += (size_t)MROWS * D_MODEL * 2;
  u16* wqkvs = (u16*)(ws + off); off += (size_t)NQKV * D_MODEL * 2;
  u16* wos   = (u16*)(ws + off); off += (size_t)D_MODEL * D_MODEL * 2;
  u16* qkvb  = (u16*)(ws + off); off += (size_t)MROWS * NQKV * 2;
  u16* ao    = (u16*)(ws + off); off += (size_t)MROWS * D_MODEL * 2;
  u16* vt    = (u16*)(ws + off); off += (size_t)512 * MROWS * 2;

  // 1. fused prep: weight signs + |w| partials + x->bf16
  prep_all<<<1152, 256, 0, stream>>>(wq, wk, wv, wo, x, wqkvs, wos, xb, partials);
  finalize_scales<<<1, 64, 0, stream>>>(partials, tabs);

  // 2. fused QKV projection; V columns stored transposed into vt
  gemm_bt<1, 1><<<dim3(NQKV / 128, MROWS / 128), 256, 0, stream>>>(
      xb, wqkvs, qkvb, tabs, vt, MROWS, NQKV, D_MODEL);

  // 3. GQA causal flash attention (paired, XCD-pinned, split loops)
  flash_attn<<<dim3(8, 64), 256, 0, stream>>>(qkvb, vt, ao);

  // 4. output projection (f32 out)
  gemm_bt<0, 0><<<dim3(D_MODEL / 128, MROWS / 128), 256, 0, stream>>>(
      ao, wos, out, tabs + 24, nullptr, MROWS, D_MODEL, D_MODEL);
}

// Round 10
// 195.866 us; speedup vs baseline: 1.9619x; 1.0184x over previous
//
#include <hip/hip_runtime.h>
#include <stdint.h>

// ---------------------------------------------------------------------------
// BitAttention round 9 (additive):
//   - gemm_bt: __launch_bounds__(256,4) -> 4 blocks/CU (was 2); VGPR<=128
//     (acc 64 + frags 32 + addr fits) -> more cross-block overlap of the
//     barrier drain (m114 mechanism)
//   - finalize_scales: 4-wave parallel butterfly reduce (was 1-thread loop)
//   - flash_attn: stage(t+1) issued BEFORE QK^T(t) -> vmcnt covered by the
//     whole tile; structure otherwise = round-8 (75.8 us known-good)
// ws layout (bytes):
//   [0,5120)    double partials[640]
//   [6144,6304) float tabs[40]
//   [8192,...)  xb(16M) wqkvs(12M) wos(8M) qkvb(24M) ao(16M) vt(4M)
// ---------------------------------------------------------------------------

#define D_MODEL 2048
#define S_LEN   2048
#define BATCH   2
#define NKV     8
#define HD      64
#define MROWS   (BATCH * S_LEN)   // 4096
#define NQKV    3072
#define LDQKV   3072

typedef unsigned short u16;
typedef __bf16 bf16x8 __attribute__((ext_vector_type(8)));
typedef float  f32x4  __attribute__((ext_vector_type(4)));

__device__ __forceinline__ u16 f2bf(float f) {
  union { float f; unsigned u; } v; v.f = f;
  unsigned r = v.u + 0x7FFFu + ((v.u >> 16) & 1u);   // RNE
  return (u16)(r >> 16);
}

__device__ __forceinline__ float exp2_fast(float x) {
  float r; asm("v_exp_f32 %0, %1" : "=v"(r) : "v"(x)); return r;
}

__device__ __forceinline__ unsigned cvt_pk_bf16(float a, float b) {
  unsigned r;
  asm("v_cvt_pk_bf16_f32 %0, %1, %2" : "=v"(r) : "v"(a), "v"(b));
  return r;
}

__device__ __forceinline__ void lds_load16(u16* lds, const u16* g) {
  __builtin_amdgcn_global_load_lds(
      (const __attribute__((address_space(1))) void*)g,
      (__attribute__((address_space(3))) void*)lds, 16, 0, 0);
}

#define SM_LOG2E 0.180336880f   // (1/sqrt(64)) * log2(e); folded into Q cols
#define THR_LOG2 11.5415603f    // 8 * log2(e)

// ---------------- fused prep: weight sign+|w| partials, x->bf16 ----------------
__global__ void prep_all(const float* __restrict__ wq, const float* __restrict__ wk,
                         const float* __restrict__ wv, const float* __restrict__ wo,
                         const float* __restrict__ x,
                         u16* __restrict__ wqkvs, u16* __restrict__ wos,
                         u16* __restrict__ xb, double* __restrict__ partials) {
  const int bid = blockIdx.x;
  const float* src; u16* dst; int n4, rb, nb; bool sgn = true;
  if (bid < 256)      { src = wq; dst = wqkvs;                  n4 = 1048576; rb = bid;       nb = 256; }
  else if (bid < 320) { src = wk; dst = wqkvs + 2048 * D_MODEL; n4 = 262144;  rb = bid - 256; nb = 64;  }
  else if (bid < 384) { src = wv; dst = wqkvs + 2560 * D_MODEL; n4 = 262144;  rb = bid - 320; nb = 64;  }
  else if (bid < 640) { src = wo; dst = wos;                    n4 = 1048576; rb = bid - 384; nb = 256; }
  else                { src = x;  dst = xb;                     n4 = 2097152; rb = bid - 640; nb = 512; sgn = false; }

  if (sgn) {
    double s = 0.0;
    for (int i = rb * 256 + threadIdx.x; i < n4; i += nb * 256) {
      float4 v = reinterpret_cast<const float4*>(src)[i];
      ushort4 o;
      o.x = v.x > 0.f ? 0x3F80 : (v.x < 0.f ? 0xBF80 : 0);
      o.y = v.y > 0.f ? 0x3F80 : (v.y < 0.f ? 0xBF80 : 0);
      o.z = v.z > 0.f ? 0x3F80 : (v.z < 0.f ? 0xBF80 : 0);
      o.w = v.w > 0.f ? 0x3F80 : (v.w < 0.f ? 0xBF80 : 0);
      reinterpret_cast<ushort4*>(dst)[i] = o;
      s += (double)fabsf(v.x) + (double)fabsf(v.y) +
           (double)fabsf(v.z) + (double)fabsf(v.w);
    }
    __shared__ double sm[256];
    sm[threadIdx.x] = s;
    __syncthreads();
    for (int off = 128; off > 0; off >>= 1) {
      if (threadIdx.x < off) sm[threadIdx.x] += sm[threadIdx.x + off];
      __syncthreads();
    }
    if (threadIdx.x == 0) partials[bid] = sm[0];
  } else {
    for (int i = rb * 256 + threadIdx.x; i < n4; i += nb * 256) {
      float4 v = reinterpret_cast<const float4*>(src)[i];
      ushort4 o;
      o.x = f2bf(v.x); o.y = f2bf(v.y); o.z = f2bf(v.z); o.w = f2bf(v.w);
      reinterpret_cast<ushort4*>(dst)[i] = o;
    }
  }
}

// 4 waves, one per weight; butterfly reduce (deterministic fixed tree).
__global__ void finalize_scales(const double* __restrict__ partials,
                                float* __restrict__ tabs) {
  __shared__ float sc_sh[4];
  const int w = threadIdx.x >> 6;
  const int lane = threadIdx.x & 63;
  const int beg[4] = {0, 256, 320, 384};
  const int cnt[4] = {256, 64, 64, 256};
  const double counts[4] = {4194304.0, 1048576.0, 1048576.0, 4194304.0};
  double s = 0.0;
  for (int i = lane; i < cnt[w]; i += 64) s += partials[beg[w] + i];
  for (int off = 1; off < 64; off <<= 1) s += __shfl_xor(s, off);
  if (lane == 0) sc_sh[w] = fmaxf((float)(s / counts[w]), 1e-5f);
  __syncthreads();
  if (threadIdx.x == 0) {
    const float s0 = sc_sh[0], s1 = sc_sh[1], s2 = sc_sh[2], s3 = sc_sh[3];
    for (int i = 0; i < 24; ++i)
      tabs[i] = (i < 16) ? s0 * SM_LOG2E : (i < 20 ? s1 : s2);
    for (int i = 0; i < 16; ++i) tabs[24 + i] = s3;
  }
}

// ---------------- GEMM: C[m,n] = tab[bx] * sum_k A[m,k]*Bt[n,k] ----------------
// VSPLIT: blocks with bx>=20 (V columns) store TRANSPOSED into vt[512][4096].
template <int OUT_BF16, int VSPLIT>
__global__ __launch_bounds__(256, 4) void gemm_bt(
    const u16* __restrict__ A, const u16* __restrict__ Bt, void* __restrict__ Cv,
    const float* __restrict__ tab, u16* __restrict__ vt, int M, int N, int K) {
  __shared__ u16 lA[128 * 64];
  __shared__ u16 lB[128 * 64];
  const int tid = threadIdx.x;
  const int lane = tid & 63, wave = tid >> 6;
  const int lo = lane & 15, hi = lane >> 4;
  const int m0 = blockIdx.y * 128, n0 = blockIdx.x * 128;
  const int wr = (wave >> 1) * 64, wc = (wave & 1) * 64;

  f32x4 acc[4][4] = {};

  for (int k0 = 0; k0 < K; k0 += 64) {
#pragma unroll
    for (int it = 0; it < 4; ++it) {
      const int c = it * 256 + wave * 64 + lane;
      const int row = c >> 3, kc = (c & 7) << 3;
      lds_load16(&lA[(it * 256 + wave * 64) * 8], &A[(size_t)(m0 + row) * K + k0 + kc]);
      lds_load16(&lB[(it * 256 + wave * 64) * 8], &Bt[(size_t)(n0 + row) * K + k0 + kc]);
    }
    __syncthreads();
#pragma unroll
    for (int kk = 0; kk < 2; ++kk) {
      bf16x8 af[4], bfr[4];
#pragma unroll
      for (int i = 0; i < 4; ++i)
        af[i] = *reinterpret_cast<const bf16x8*>(&lA[(wr + i * 16 + lo) * 64 + kk * 32 + hi * 8]);
#pragma unroll
      for (int i = 0; i < 4; ++i)
        bfr[i] = *reinterpret_cast<const bf16x8*>(&lB[(wc + i * 16 + lo) * 64 + kk * 32 + hi * 8]);
#pragma unroll
      for (int mi = 0; mi < 4; ++mi)
#pragma unroll
        for (int ni = 0; ni < 4; ++ni)
          acc[mi][ni] = __builtin_amdgcn_mfma_f32_16x16x32_bf16(af[mi], bfr[ni], acc[mi][ni], 0, 0, 0);
    }
    __syncthreads();
  }

  const float scale = tab[blockIdx.x];
  if (VSPLIT && (int)blockIdx.x >= 20) {
    // V columns: transposed store, 4 consecutive rows (m) packed per dwordx2
#pragma unroll
    for (int mi = 0; mi < 4; ++mi) {
#pragma unroll
      for (int ni = 0; ni < 4; ++ni) {
        const int col = (n0 - 2560) + wc + ni * 16 + lo;       // 0..511
        const int row = m0 + wr + mi * 16 + hi * 4;            // mult of 4
        unsigned w01 = (unsigned)f2bf(acc[mi][ni][0] * scale) |
                       ((unsigned)f2bf(acc[mi][ni][1] * scale) << 16);
        unsigned w23 = (unsigned)f2bf(acc[mi][ni][2] * scale) |
                       ((unsigned)f2bf(acc[mi][ni][3] * scale) << 16);
        uint2 pk; pk.x = w01; pk.y = w23;
        *reinterpret_cast<uint2*>(vt + (size_t)col * MROWS + row) = pk;
      }
    }
    return;
  }
#pragma unroll
  for (int mi = 0; mi < 4; ++mi) {
#pragma unroll
    for (int ni = 0; ni < 4; ++ni) {
#pragma unroll
      for (int r = 0; r < 4; ++r) {
        const int row = m0 + wr + mi * 16 + hi * 4 + r;
        const int col = n0 + wc + ni * 16 + lo;
        const float v = acc[mi][ni][r] * scale;
        if (OUT_BF16)
          reinterpret_cast<u16*>(Cv)[(size_t)row * N + col] = f2bf(v);
        else
          reinterpret_cast<float*>(Cv)[(size_t)row * N + col] = v;
      }
    }
  }
}

// ---------------- flash attention v9 (GQA, causal, paired, split loops) --------
__device__ __forceinline__ void stage_tile(u16* dst, const u16* base, int ld,
                                           int tid, int wave) {
#pragma unroll
  for (int it = 0; it < 2; ++it) {
    const int c = it * 256 + tid;
    const int row = c >> 3;
    const int ch = (c & 7) ^ (row & 7);   // pre-swizzled source (rule #21)
    lds_load16(dst + (it * 256 + wave * 64) * 8, base + (size_t)row * ld + ch * 8);
  }
}

// One KV-tile step. MASKED=1 only for the 2 diagonal tiles.
// stage(t+1) is issued FIRST so its latency is covered by the whole tile.
#define TILE_BODY(MASKED)                                                      \
  {                                                                            \
    const int t0 = ti * 64;                                                    \
    const int cur = ti & 1;                                                    \
    u16* lKc = (u16*)lK[cur];                                                  \
    u16* lVc = (u16*)lV[cur];                                                  \
    if (ti + 1 < nt) {                                                         \
      stage_tile(lK[cur ^ 1], Kb + (size_t)(brow + t0 + 64) * LDQKV, LDQKV,    \
                 tid, wave);                                                   \
      stage_tile(lV[cur ^ 1], Vb + t0 + 64, MROWS, tid, wave);                 \
    }                                                                          \
    f32x4 sacc[2][4] = {};                                                     \
    __builtin_amdgcn_s_setprio(1);                                             \
    _Pragma("unroll")                                                          \
    for (int kk = 0; kk < 2; ++kk) {                                           \
      _Pragma("unroll")                                                        \
      for (int nf = 0; nf < 4; ++nf) {                                         \
        bf16x8 kf = *reinterpret_cast<const bf16x8*>(                          \
            &lKc[(nf * 16 + lo) * 64 + ((kk * 32 + hi * 8) ^ swl)]);           \
        _Pragma("unroll")                                                      \
        for (int mi = 0; mi < 2; ++mi)                                         \
          sacc[mi][nf] = __builtin_amdgcn_mfma_f32_16x16x32_bf16(              \
              kf, qf[mi][kk], sacc[mi][nf], 0, 0, 0);                          \
      }                                                                        \
    }                                                                          \
    __builtin_amdgcn_s_setprio(0);                                             \
    float rowmax[2];                                                           \
    bool ok = true;                                                            \
    _Pragma("unroll")                                                          \
    for (int mi = 0; mi < 2; ++mi) {                                           \
      if (MASKED) {                                                            \
        const int qg = q0w + mi * 16 + lo;                                     \
        _Pragma("unroll")                                                      \
        for (int nf = 0; nf < 4; ++nf) {                                       \
          _Pragma("unroll")                                                    \
          for (int r = 0; r < 4; ++r) {                                        \
            const int tg = t0 + nf * 16 + hi * 4 + r;                          \
            if (tg > qg) sacc[mi][nf][r] = -1e30f;                             \
          }                                                                    \
        }                                                                      \
      }                                                                        \
      float mnf[4];                                                            \
      _Pragma("unroll")                                                        \
      for (int nf = 0; nf < 4; ++nf)                                           \
        mnf[nf] = fmaxf(fmaxf(sacc[mi][nf][0], sacc[mi][nf][1]),               \
                        fmaxf(sacc[mi][nf][2], sacc[mi][nf][3]));              \
      float mt = fmaxf(fmaxf(mnf[0], mnf[1]), fmaxf(mnf[2], mnf[3]));          \
      mt = fmaxf(mt, __shfl_xor(mt, 16));                                      \
      mt = fmaxf(mt, __shfl_xor(mt, 32));                                      \
      rowmax[mi] = mt;                                                         \
      ok = ok && (mt <= m_run[mi] + THR_LOG2);                                 \
    }                                                                          \
    if (!__all((int)ok)) {                                                     \
      _Pragma("unroll")                                                        \
      for (int mi = 0; mi < 2; ++mi) {                                         \
        const float mn = fmaxf(m_run[mi], rowmax[mi]);                         \
        const float alpha = exp2_fast(m_run[mi] - mn);                         \
        m_run[mi] = mn;                                                        \
        l_lane[mi] *= alpha;                                                   \
        const float a0 = __shfl(alpha, xbase + 0);                             \
        const float a1 = __shfl(alpha, xbase + 1);                             \
        const float a2 = __shfl(alpha, xbase + 2);                             \
        const float a3 = __shfl(alpha, xbase + 3);                             \
        _Pragma("unroll")                                                      \
        for (int nf = 0; nf < 4; ++nf) {                                       \
          oacc[mi][nf][0] *= a0; oacc[mi][nf][1] *= a1;                        \
          oacc[mi][nf][2] *= a2; oacc[mi][nf][3] *= a3;                        \
        }                                                                      \
      }                                                                        \
    }                                                                          \
    _Pragma("unroll")                                                          \
    for (int mi = 0; mi < 2; ++mi) {                                           \
      u16* lprow = &lP[wave][(mi * 16 + lo) * 72 + hi * 4];                    \
      float ls = 0.f;                                                          \
      _Pragma("unroll")                                                        \
      for (int nf = 0; nf < 4; ++nf) {                                         \
        const float e0 = exp2_fast(sacc[mi][nf][0] - m_run[mi]);               \
        const float e1 = exp2_fast(sacc[mi][nf][1] - m_run[mi]);               \
        const float e2 = exp2_fast(sacc[mi][nf][2] - m_run[mi]);               \
        const float e3 = exp2_fast(sacc[mi][nf][3] - m_run[mi]);               \
        ls += (e0 + e1) + (e2 + e3);                                           \
        uint2 pk; pk.x = cvt_pk_bf16(e0, e1); pk.y = cvt_pk_bf16(e2, e3);      \
        *reinterpret_cast<uint2*>(lprow + nf * 16) = pk;                       \
      }                                                                        \
      l_lane[mi] += ls;                                                        \
    }                                                                          \
    __builtin_amdgcn_s_setprio(1);                                             \
    _Pragma("unroll")                                                          \
    for (int kk = 0; kk < 2; ++kk) {                                           \
      bf16x8 pf[2];                                                            \
      _Pragma("unroll")                                                        \
      for (int mi = 0; mi < 2; ++mi)                                           \
        pf[mi] = *reinterpret_cast<const bf16x8*>(                             \
            &lP[wave][(mi * 16 + lo) * 72 + kk * 32 + hi * 8]);                \
      _Pragma("unroll")                                                        \
      for (int nf = 0; nf < 4; ++nf) {                                         \
        bf16x8 vf = *reinterpret_cast<const bf16x8*>(                          \
            &lVc[(nf * 16 + lo) * 64 + ((kk * 32 + hi * 8) ^ swl)]);           \
        _Pragma("unroll")                                                      \
        for (int mi = 0; mi < 2; ++mi)                                         \
          oacc[mi][nf] = __builtin_amdgcn_mfma_f32_16x16x32_bf16(              \
              pf[mi], vf, oacc[mi][nf], 0, 0, 0);                              \
      }                                                                        \
    }                                                                          \
    __builtin_amdgcn_s_setprio(0);                                             \
    __syncthreads();                                                           \
  }

__global__ __launch_bounds__(256, 2) void flash_attn(
    const u16* __restrict__ QKV, const u16* __restrict__ VT,
    u16* __restrict__ Og) {
  __shared__ u16 lK[2][64 * 64];    // [t][d], XOR-swizzled chunks
  __shared__ u16 lV[2][64 * 64];    // [d][t], XOR-swizzled chunks
  __shared__ u16 lP[4][32 * 72];    // per-wave P[q][t], stride 72

  const int tid = threadIdx.x;
  const int lane = tid & 63, wave = tid >> 6;
  const int lo = lane & 15, hi = lane >> 4;
  // XCD group pinning: linear id mod 8 ~ XCD; give each (b,kv) group's 32
  // blocks one residue class -> K/V^T (512KB/group, 2 groups/XCD) L2-resident.
  const int lin = (int)blockIdx.y * 8 + (int)blockIdx.x;   // 0..511
  const int xcd = lin & 7, slot = lin >> 3;
  const int G = xcd * 2 + (slot >> 5);    // 0..15 = (b, kv)
  const int wb = slot & 31;               // 0..31 = (g_h, lbx)
  const int b = G >> 3, kv = G & 7;
  const int h = kv * 4 + (wb >> 3);
  const int lbx = wb & 7;
  const int brow = b * S_LEN;
  const u16* Q  = QKV + h * HD;
  const u16* Kb = QKV + 2048 + kv * HD;                   // row stride LDQKV
  const u16* Vb = VT + (size_t)(kv * HD) * MROWS + brow;  // row d, stride MROWS
  const int swl = (lo & 7) << 3;
  const int xbase = (lane & 48) | ((lane >> 2) & 12);     // lane with lo=hi*4(+r)

#pragma unroll 1
  for (int pi = 0; pi < 2; ++pi) {
    const int qt = pi == 0 ? lbx : (15 - lbx);
    const int q0 = qt * 128;
    const int q0w = q0 + wave * 32;
    const int nt = 2 * qt + 2;

    // Q fragments resident for the pass (pre-scaled by sm_scale*log2e)
    bf16x8 qf[2][2];
#pragma unroll
    for (int mi = 0; mi < 2; ++mi) {
      const size_t qr = (size_t)(brow + q0w + mi * 16 + lo) * LDQKV;
#pragma unroll
      for (int kk = 0; kk < 2; ++kk)
        qf[mi][kk] = *reinterpret_cast<const bf16x8*>(&Q[qr + kk * 32 + hi * 8]);
    }

    f32x4 oacc[2][4] = {};
    float m_run[2] = {-1e30f, -1e30f};
    float l_lane[2] = {0.f, 0.f};

    // prologue: stage tile 0 into buffer 0
    stage_tile(lK[0], Kb + (size_t)brow * LDQKV, LDQKV, tid, wave);
    stage_tile(lV[0], Vb, MROWS, tid, wave);
    __syncthreads();

    // full tiles: no causal masking needed (t0+64 <= q0)
#pragma unroll 1
    for (int ti = 0; ti < 2 * qt; ++ti) TILE_BODY(0)
    // diagonal tiles (2): per-element masking
#pragma unroll 1
    for (int ti = 2 * qt; ti < nt; ++ti) TILE_BODY(1)

    // ---- epilogue: finish l across hi-group, redistribute, store ----
#pragma unroll
    for (int mi = 0; mi < 2; ++mi) {
      float ls = l_lane[mi];
      ls += __shfl_xor(ls, 16);
      ls += __shfl_xor(ls, 32);
      const float inv = 1.f / ls;
      const float i0 = __shfl(inv, xbase + 0);
      const float i1 = __shfl(inv, xbase + 1);
      const float i2 = __shfl(inv, xbase + 2);
      const float i3 = __shfl(inv, xbase + 3);
#pragma unroll
      for (int nf = 0; nf < 4; ++nf) {
        const size_t rb0 = (size_t)(brow + q0w + mi * 16 + hi * 4) * D_MODEL +
                           h * HD + nf * 16 + lo;
        Og[rb0 + 0 * D_MODEL] = f2bf(oacc[mi][nf][0] * i0);
        Og[rb0 + 1 * D_MODEL] = f2bf(oacc[mi][nf][1] * i1);
        Og[rb0 + 2 * D_MODEL] = f2bf(oacc[mi][nf][2] * i2);
        Og[rb0 + 3 * D_MODEL] = f2bf(oacc[mi][nf][3] * i3);
      }
    }
  }
}

// ---------------- launcher ----------------
extern "C" void kernel_launch(void* const* d_in, const int* in_sizes, int n_in,
                              void* d_out, int out_size, void* d_ws, size_t ws_size,
                              hipStream_t stream) {
  (void)in_sizes; (void)n_in; (void)out_size; (void)ws_size;
  const float* x  = (const float*)d_in[0];
  const float* wq = (const float*)d_in[1];
  const float* wk = (const float*)d_in[2];
  const float* wv = (const float*)d_in[3];
  const float* wo = (const float*)d_in[4];
  float* out = (float*)d_out;
  char* ws = (char*)d_ws;

  double* partials = (double*)ws;            // 640 * 8 B
  float* tabs = (float*)(ws + 6144);         // 40 floats
  size_t off = 8192;
  u16* xb    = (u16*)(ws + off); off += (size_t)MROWS * D_MODEL * 2;
  u16* wqkvs = (u16*)(ws + off); off += (size_t)NQKV * D_MODEL * 2;
  u16* wos   = (u16*)(ws + off); off += (size_t)D_MODEL * D_MODEL * 2;
  u16* qkvb  = (u16*)(ws + off); off += (size_t)MROWS * NQKV * 2;
  u16* ao    = (u16*)(ws + off); off += (size_t)MROWS * D_MODEL * 2;
  u16* vt    = (u16*)(ws + off); off += (size_t)512 * MROWS * 2;

  // 1. fused prep: weight signs + |w| partials + x->bf16
  prep_all<<<1152, 256, 0, stream>>>(wq, wk, wv, wo, x, wqkvs, wos, xb, partials);
  finalize_scales<<<1, 256, 0, stream>>>(partials, tabs);

  // 2. fused QKV projection; V columns stored transposed into vt
  gemm_bt<1, 1><<<dim3(NQKV / 128, MROWS / 128), 256, 0, stream>>>(
      xb, wqkvs, qkvb, tabs, vt, MROWS, NQKV, D_MODEL);

  // 3. GQA causal flash attention (paired, XCD-pinned, split loops)
  flash_attn<<<dim3(8, 64), 256, 0, stream>>>(qkvb, vt, ao);

  // 4. output projection (f32 out)
  gemm_bt<0, 0><<<dim3(D_MODEL / 128, MROWS / 128), 256, 0, stream>>>(
      ao, wos, out, tabs + 24, nullptr, MROWS, D_MODEL, D_MODEL);
}

// Round 11
// 185.314 us; speedup vs baseline: 2.0736x; 1.0569x over previous
//
#include <hip/hip_runtime.h>
#include <stdint.h>

// ---------------------------------------------------------------------------
// BitAttention round 10:
//   - flash_attn v10: 32x32x16 MFMA + permlane32_swap P-redistribution (T12).
//     No lP LDS at all; alpha/l lane-local (q = lane&31); 1-shfl row max;
//     packed 8B O-stores. Paired grid + XCD pinning + causal split kept.
//     Stage order reverted to post-QK^T (round-8's 75.8us order).
//   - gemm_bt (256,4), parallel finalize, prep_all: unchanged from round 9.
// ws layout (bytes):
//   [0,5120)    double partials[640]
//   [6144,6304) float tabs[40]
//   [8192,...)  xb(16M) wqkvs(12M) wos(8M) qkvb(24M) ao(16M) vt(4M)
// ---------------------------------------------------------------------------

#define D_MODEL 2048
#define S_LEN   2048
#define BATCH   2
#define NKV     8
#define HD      64
#define MROWS   (BATCH * S_LEN)   // 4096
#define NQKV    3072
#define LDQKV   3072

typedef unsigned short u16;
typedef __bf16 bf16x8 __attribute__((ext_vector_type(8)));
typedef float  f32x4  __attribute__((ext_vector_type(4)));
typedef float  f32x16 __attribute__((ext_vector_type(16)));
typedef unsigned u32x4 __attribute__((ext_vector_type(4)));

__device__ __forceinline__ u16 f2bf(float f) {
  union { float f; unsigned u; } v; v.f = f;
  unsigned r = v.u + 0x7FFFu + ((v.u >> 16) & 1u);   // RNE
  return (u16)(r >> 16);
}

__device__ __forceinline__ float exp2_fast(float x) {
  float r; asm("v_exp_f32 %0, %1" : "=v"(r) : "v"(x)); return r;
}

__device__ __forceinline__ unsigned cvt_pk_bf16(float a, float b) {
  unsigned r;
  asm("v_cvt_pk_bf16_f32 %0, %1, %2" : "=v"(r) : "v"(a), "v"(b));
  return r;
}

__device__ __forceinline__ void lds_load16(u16* lds, const u16* g) {
  __builtin_amdgcn_global_load_lds(
      (const __attribute__((address_space(1))) void*)g,
      (__attribute__((address_space(3))) void*)lds, 16, 0, 0);
}

#define SM_LOG2E 0.180336880f   // (1/sqrt(64)) * log2(e); folded into Q cols
#define THR_LOG2 11.5415603f    // 8 * log2(e)

// ---------------- fused prep: weight sign+|w| partials, x->bf16 ----------------
__global__ void prep_all(const float* __restrict__ wq, const float* __restrict__ wk,
                         const float* __restrict__ wv, const float* __restrict__ wo,
                         const float* __restrict__ x,
                         u16* __restrict__ wqkvs, u16* __restrict__ wos,
                         u16* __restrict__ xb, double* __restrict__ partials) {
  const int bid = blockIdx.x;
  const float* src; u16* dst; int n4, rb, nb; bool sgn = true;
  if (bid < 256)      { src = wq; dst = wqkvs;                  n4 = 1048576; rb = bid;       nb = 256; }
  else if (bid < 320) { src = wk; dst = wqkvs + 2048 * D_MODEL; n4 = 262144;  rb = bid - 256; nb = 64;  }
  else if (bid < 384) { src = wv; dst = wqkvs + 2560 * D_MODEL; n4 = 262144;  rb = bid - 320; nb = 64;  }
  else if (bid < 640) { src = wo; dst = wos;                    n4 = 1048576; rb = bid - 384; nb = 256; }
  else                { src = x;  dst = xb;                     n4 = 2097152; rb = bid - 640; nb = 512; sgn = false; }

  if (sgn) {
    double s = 0.0;
    for (int i = rb * 256 + threadIdx.x; i < n4; i += nb * 256) {
      float4 v = reinterpret_cast<const float4*>(src)[i];
      ushort4 o;
      o.x = v.x > 0.f ? 0x3F80 : (v.x < 0.f ? 0xBF80 : 0);
      o.y = v.y > 0.f ? 0x3F80 : (v.y < 0.f ? 0xBF80 : 0);
      o.z = v.z > 0.f ? 0x3F80 : (v.z < 0.f ? 0xBF80 : 0);
      o.w = v.w > 0.f ? 0x3F80 : (v.w < 0.f ? 0xBF80 : 0);
      reinterpret_cast<ushort4*>(dst)[i] = o;
      s += (double)fabsf(v.x) + (double)fabsf(v.y) +
           (double)fabsf(v.z) + (double)fabsf(v.w);
    }
    __shared__ double sm[256];
    sm[threadIdx.x] = s;
    __syncthreads();
    for (int off = 128; off > 0; off >>= 1) {
      if (threadIdx.x < off) sm[threadIdx.x] += sm[threadIdx.x + off];
      __syncthreads();
    }
    if (threadIdx.x == 0) partials[bid] = sm[0];
  } else {
    for (int i = rb * 256 + threadIdx.x; i < n4; i += nb * 256) {
      float4 v = reinterpret_cast<const float4*>(src)[i];
      ushort4 o;
      o.x = f2bf(v.x); o.y = f2bf(v.y); o.z = f2bf(v.z); o.w = f2bf(v.w);
      reinterpret_cast<ushort4*>(dst)[i] = o;
    }
  }
}

// 4 waves, one per weight; butterfly reduce (deterministic fixed tree).
__global__ void finalize_scales(const double* __restrict__ partials,
                                float* __restrict__ tabs) {
  __shared__ float sc_sh[4];
  const int w = threadIdx.x >> 6;
  const int lane = threadIdx.x & 63;
  const int beg[4] = {0, 256, 320, 384};
  const int cnt[4] = {256, 64, 64, 256};
  const double counts[4] = {4194304.0, 1048576.0, 1048576.0, 4194304.0};
  double s = 0.0;
  for (int i = lane; i < cnt[w]; i += 64) s += partials[beg[w] + i];
  for (int off = 1; off < 64; off <<= 1) s += __shfl_xor(s, off);
  if (lane == 0) sc_sh[w] = fmaxf((float)(s / counts[w]), 1e-5f);
  __syncthreads();
  if (threadIdx.x == 0) {
    const float s0 = sc_sh[0], s1 = sc_sh[1], s2 = sc_sh[2], s3 = sc_sh[3];
    for (int i = 0; i < 24; ++i)
      tabs[i] = (i < 16) ? s0 * SM_LOG2E : (i < 20 ? s1 : s2);
    for (int i = 0; i < 16; ++i) tabs[24 + i] = s3;
  }
}

// ---------------- GEMM: C[m,n] = tab[bx] * sum_k A[m,k]*Bt[n,k] ----------------
// VSPLIT: blocks with bx>=20 (V columns) store TRANSPOSED into vt[512][4096].
template <int OUT_BF16, int VSPLIT>
__global__ __launch_bounds__(256, 4) void gemm_bt(
    const u16* __restrict__ A, const u16* __restrict__ Bt, void* __restrict__ Cv,
    const float* __restrict__ tab, u16* __restrict__ vt, int M, int N, int K) {
  __shared__ u16 lA[128 * 64];
  __shared__ u16 lB[128 * 64];
  const int tid = threadIdx.x;
  const int lane = tid & 63, wave = tid >> 6;
  const int lo = lane & 15, hi = lane >> 4;
  const int m0 = blockIdx.y * 128, n0 = blockIdx.x * 128;
  const int wr = (wave >> 1) * 64, wc = (wave & 1) * 64;

  f32x4 acc[4][4] = {};

  for (int k0 = 0; k0 < K; k0 += 64) {
#pragma unroll
    for (int it = 0; it < 4; ++it) {
      const int c = it * 256 + wave * 64 + lane;
      const int row = c >> 3, kc = (c & 7) << 3;
      lds_load16(&lA[(it * 256 + wave * 64) * 8], &A[(size_t)(m0 + row) * K + k0 + kc]);
      lds_load16(&lB[(it * 256 + wave * 64) * 8], &Bt[(size_t)(n0 + row) * K + k0 + kc]);
    }
    __syncthreads();
#pragma unroll
    for (int kk = 0; kk < 2; ++kk) {
      bf16x8 af[4], bfr[4];
#pragma unroll
      for (int i = 0; i < 4; ++i)
        af[i] = *reinterpret_cast<const bf16x8*>(&lA[(wr + i * 16 + lo) * 64 + kk * 32 + hi * 8]);
#pragma unroll
      for (int i = 0; i < 4; ++i)
        bfr[i] = *reinterpret_cast<const bf16x8*>(&lB[(wc + i * 16 + lo) * 64 + kk * 32 + hi * 8]);
#pragma unroll
      for (int mi = 0; mi < 4; ++mi)
#pragma unroll
        for (int ni = 0; ni < 4; ++ni)
          acc[mi][ni] = __builtin_amdgcn_mfma_f32_16x16x32_bf16(af[mi], bfr[ni], acc[mi][ni], 0, 0, 0);
    }
    __syncthreads();
  }

  const float scale = tab[blockIdx.x];
  if (VSPLIT && (int)blockIdx.x >= 20) {
    // V columns: transposed store, 4 consecutive rows (m) packed per dwordx2
#pragma unroll
    for (int mi = 0; mi < 4; ++mi) {
#pragma unroll
      for (int ni = 0; ni < 4; ++ni) {
        const int col = (n0 - 2560) + wc + ni * 16 + lo;       // 0..511
        const int row = m0 + wr + mi * 16 + hi * 4;            // mult of 4
        unsigned w01 = (unsigned)f2bf(acc[mi][ni][0] * scale) |
                       ((unsigned)f2bf(acc[mi][ni][1] * scale) << 16);
        unsigned w23 = (unsigned)f2bf(acc[mi][ni][2] * scale) |
                       ((unsigned)f2bf(acc[mi][ni][3] * scale) << 16);
        uint2 pk; pk.x = w01; pk.y = w23;
        *reinterpret_cast<uint2*>(vt + (size_t)col * MROWS + row) = pk;
      }
    }
    return;
  }
#pragma unroll
  for (int mi = 0; mi < 4; ++mi) {
#pragma unroll
    for (int ni = 0; ni < 4; ++ni) {
#pragma unroll
      for (int r = 0; r < 4; ++r) {
        const int row = m0 + wr + mi * 16 + hi * 4 + r;
        const int col = n0 + wc + ni * 16 + lo;
        const float v = acc[mi][ni][r] * scale;
        if (OUT_BF16)
          reinterpret_cast<u16*>(Cv)[(size_t)row * N + col] = f2bf(v);
        else
          reinterpret_cast<float*>(Cv)[(size_t)row * N + col] = v;
      }
    }
  }
}

// ---------------- flash attention v10 (32x32 MFMA + permlane, causal) ----------
__device__ __forceinline__ void stage_tile(u16* dst, const u16* base, int ld,
                                           int tid, int wave) {
#pragma unroll
  for (int it = 0; it < 2; ++it) {
    const int c = it * 256 + tid;
    const int row = c >> 3;
    const int ch = (c & 7) ^ (row & 7);   // pre-swizzled source (rule #21)
    lds_load16(dst + (it * 256 + wave * 64) * 8, base + (size_t)row * ld + ch * 8);
  }
}

// One KV-tile step. MASKED=1 only for the 2 diagonal tiles.
// S^T via mfma32(K,Q): lane holds q = lane&31; t = (rg&3)+8*(rg>>2)+4*hi5+32*nf.
#define TILE_BODY(MASKED)                                                      \
  {                                                                            \
    const int t0 = ti * 64;                                                    \
    const int cur = ti & 1;                                                    \
    u16* lKc = (u16*)lK[cur];                                                  \
    u16* lVc = (u16*)lV[cur];                                                  \
    f32x16 sacc[2] = {};                                                       \
    __builtin_amdgcn_s_setprio(1);                                             \
    _Pragma("unroll")                                                          \
    for (int w = 0; w < 4; ++w) {                                              \
      _Pragma("unroll")                                                        \
      for (int nf = 0; nf < 2; ++nf) {                                         \
        bf16x8 kf = *reinterpret_cast<const bf16x8*>(                          \
            &lKc[(nf * 32 + q31) * 64 + ((w * 16 + hi5 * 8) ^ swl)]);          \
        sacc[nf] = __builtin_amdgcn_mfma_f32_32x32x16_bf16(                    \
            kf, qf[w], sacc[nf], 0, 0, 0);                                     \
      }                                                                        \
    }                                                                          \
    __builtin_amdgcn_s_setprio(0);                                             \
    if (ti + 1 < nt) {                                                         \
      stage_tile(lK[cur ^ 1], Kb + (size_t)(brow + t0 + 64) * LDQKV, LDQKV,    \
                 tid, wave);                                                   \
      stage_tile(lV[cur ^ 1], Vb + t0 + 64, MROWS, tid, wave);                 \
    }                                                                          \
    if (MASKED) {                                                              \
      _Pragma("unroll")                                                        \
      for (int nf = 0; nf < 2; ++nf) {                                         \
        _Pragma("unroll")                                                      \
        for (int rg = 0; rg < 16; ++rg) {                                      \
          const int tg = t0 + nf * 32 + (rg >> 2) * 8 + hi5 * 4 + (rg & 3);    \
          if (tg > qg) sacc[nf][rg] = -1e30f;                                  \
        }                                                                      \
      }                                                                        \
    }                                                                          \
    float mt = -1e30f;                                                         \
    _Pragma("unroll")                                                          \
    for (int nf = 0; nf < 2; ++nf) {                                           \
      _Pragma("unroll")                                                        \
      for (int rg = 0; rg < 16; ++rg) mt = fmaxf(mt, sacc[nf][rg]);            \
    }                                                                          \
    mt = fmaxf(mt, __shfl_xor(mt, 32));                                        \
    if (!__all((int)(mt <= m_run + THR_LOG2))) {                               \
      const float mn = fmaxf(m_run, mt);                                       \
      const float alpha = exp2_fast(m_run - mn);                               \
      m_run = mn;                                                              \
      l_lane *= alpha;                                                         \
      _Pragma("unroll")                                                        \
      for (int nf = 0; nf < 2; ++nf) {                                         \
        _Pragma("unroll")                                                      \
        for (int rg = 0; rg < 16; ++rg) oacc[nf][rg] *= alpha;                 \
      }                                                                        \
    }                                                                          \
    unsigned pk[2][8];                                                         \
    _Pragma("unroll")                                                          \
    for (int nf = 0; nf < 2; ++nf) {                                           \
      _Pragma("unroll")                                                        \
      for (int c = 0; c < 4; ++c) {                                            \
        const float e0 = exp2_fast(sacc[nf][4 * c + 0] - m_run);               \
        const float e1 = exp2_fast(sacc[nf][4 * c + 1] - m_run);               \
        const float e2 = exp2_fast(sacc[nf][4 * c + 2] - m_run);               \
        const float e3 = exp2_fast(sacc[nf][4 * c + 3] - m_run);               \
        l_lane += (e0 + e1) + (e2 + e3);                                       \
        pk[nf][2 * c + 0] = cvt_pk_bf16(e0, e1);                               \
        pk[nf][2 * c + 1] = cvt_pk_bf16(e2, e3);                               \
      }                                                                        \
    }                                                                          \
    __builtin_amdgcn_s_setprio(1);                                             \
    _Pragma("unroll")                                                          \
    for (int w = 0; w < 4; ++w) {                                              \
      const int nf = w >> 1, c4 = (w & 1) * 4;                                 \
      unsigned a0 = pk[nf][c4 + 0], a1 = pk[nf][c4 + 1];                       \
      unsigned b0 = pk[nf][c4 + 2], b1 = pk[nf][c4 + 3];                       \
      asm volatile("v_permlane32_swap_b32 %0, %1" : "+v"(a0), "+v"(b0));       \
      asm volatile("v_permlane32_swap_b32 %0, %1" : "+v"(a1), "+v"(b1));       \
      u32x4 pw; pw.x = a0; pw.y = a1; pw.z = b0; pw.w = b1;                    \
      bf16x8 pfr = *reinterpret_cast<const bf16x8*>(&pw);                      \
      _Pragma("unroll")                                                        \
      for (int nfo = 0; nfo < 2; ++nfo) {                                      \
        bf16x8 vf = *reinterpret_cast<const bf16x8*>(                          \
            &lVc[(nfo * 32 + q31) * 64 + ((w * 16 + hi5 * 8) ^ swl)]);         \
        oacc[nfo] = __builtin_amdgcn_mfma_f32_32x32x16_bf16(                   \
            vf, pfr, oacc[nfo], 0, 0, 0);                                      \
      }                                                                        \
    }                                                                          \
    __builtin_amdgcn_s_setprio(0);                                             \
    __syncthreads();                                                           \
  }

__global__ __launch_bounds__(256, 2) void flash_attn(
    const u16* __restrict__ QKV, const u16* __restrict__ VT,
    u16* __restrict__ Og) {
  __shared__ u16 lK[2][64 * 64];    // [t][d], XOR-swizzled chunks
  __shared__ u16 lV[2][64 * 64];    // [d][t], XOR-swizzled chunks

  const int tid = threadIdx.x;
  const int lane = tid & 63, wave = tid >> 6;
  const int q31 = lane & 31, hi5 = lane >> 5;
  // XCD group pinning (round-8): each (b,kv) group's 32 blocks on one XCD.
  const int lin = (int)blockIdx.y * 8 + (int)blockIdx.x;   // 0..511
  const int xcd = lin & 7, slot = lin >> 3;
  const int G = xcd * 2 + (slot >> 5);    // 0..15 = (b, kv)
  const int wb = slot & 31;               // 0..31 = (g_h, lbx)
  const int b = G >> 3, kv = G & 7;
  const int h = kv * 4 + (wb >> 3);
  const int lbx = wb & 7;
  const int brow = b * S_LEN;
  const u16* Q  = QKV + h * HD;
  const u16* Kb = QKV + 2048 + kv * HD;                   // row stride LDQKV
  const u16* Vb = VT + (size_t)(kv * HD) * MROWS + brow;  // row d, stride MROWS
  const int swl = (lane & 7) << 3;

#pragma unroll 1
  for (int pi = 0; pi < 2; ++pi) {
    const int qt = pi == 0 ? lbx : (15 - lbx);
    const int q0 = qt * 128;
    const int q0w = q0 + wave * 32;
    const int nt = 2 * qt + 2;
    const int qg = q0w + q31;          // lane's q row

    // Q fragments: lane holds Q[q][16w + 8*hi5 .. +8] per window w
    bf16x8 qf[4];
    {
      const size_t qr = (size_t)(brow + q0w + q31) * LDQKV;
#pragma unroll
      for (int w = 0; w < 4; ++w)
        qf[w] = *reinterpret_cast<const bf16x8*>(&Q[qr + w * 16 + hi5 * 8]);
    }

    f32x16 oacc[2] = {};
    float m_run = -1e30f, l_lane = 0.f;

    // prologue: stage tile 0 into buffer 0
    stage_tile(lK[0], Kb + (size_t)brow * LDQKV, LDQKV, tid, wave);
    stage_tile(lV[0], Vb, MROWS, tid, wave);
    __syncthreads();

    // full tiles: no causal masking needed (t0+64 <= q0)
#pragma unroll 1
    for (int ti = 0; ti < 2 * qt; ++ti) TILE_BODY(0)
    // diagonal tiles (2): per-element masking
#pragma unroll 1
    for (int ti = 2 * qt; ti < nt; ++ti) TILE_BODY(1)

    // ---- epilogue: l across lane pair, lane-local normalize, packed store ----
    {
      float ls = l_lane;
      ls += __shfl_xor(ls, 32);
      const float inv = 1.f / ls;
#pragma unroll
      for (int nfo = 0; nfo < 2; ++nfo) {
#pragma unroll
        for (int c = 0; c < 4; ++c) {
          const unsigned u0 = cvt_pk_bf16(oacc[nfo][4 * c + 0] * inv,
                                          oacc[nfo][4 * c + 1] * inv);
          const unsigned u1 = cvt_pk_bf16(oacc[nfo][4 * c + 2] * inv,
                                          oacc[nfo][4 * c + 3] * inv);
          const int d = nfo * 32 + c * 8 + hi5 * 4;
          uint2 st; st.x = u0; st.y = u1;
          *reinterpret_cast<uint2*>(
              &Og[(size_t)(brow + q0w + q31) * D_MODEL + h * HD + d]) = st;
        }
      }
    }
  }
}

// ---------------- launcher ----------------
extern "C" void kernel_launch(void* const* d_in, const int* in_sizes, int n_in,
                              void* d_out, int out_size, void* d_ws, size_t ws_size,
                              hipStream_t stream) {
  (void)in_sizes; (void)n_in; (void)out_size; (void)ws_size;
  const float* x  = (const float*)d_in[0];
  const float* wq = (const float*)d_in[1];
  const float* wk = (const float*)d_in[2];
  const float* wv = (const float*)d_in[3];
  const float* wo = (const float*)d_in[4];
  float* out = (float*)d_out;
  char* ws = (char*)d_ws;

  double* partials = (double*)ws;            // 640 * 8 B
  float* tabs = (float*)(ws + 6144);         // 40 floats
  size_t off = 8192;
  u16* xb    = (u16*)(ws + off); off += (size_t)MROWS * D_MODEL * 2;
  u16* wqkvs = (u16*)(ws + off); off += (size_t)NQKV * D_MODEL * 2;
  u16* wos   = (u16*)(ws + off); off += (size_t)D_MODEL * D_MODEL * 2;
  u16* qkvb  = (u16*)(ws + off); off += (size_t)MROWS * NQKV * 2;
  u16* ao    = (u16*)(ws + off); off += (size_t)MROWS * D_MODEL * 2;
  u16* vt    = (u16*)(ws + off); off += (size_t)512 * MROWS * 2;

  // 1. fused prep: weight signs + |w| partials + x->bf16
  prep_all<<<1152, 256, 0, stream>>>(wq, wk, wv, wo, x, wqkvs, wos, xb, partials);
  finalize_scales<<<1, 256, 0, stream>>>(partials, tabs);

  // 2. fused QKV projection; V columns stored transposed into vt
  gemm_bt<1, 1><<<dim3(NQKV / 128, MROWS / 128), 256, 0, stream>>>(
      xb, wqkvs, qkvb, tabs, vt, MROWS, NQKV, D_MODEL);

  // 3. GQA causal flash attention (32x32 MFMA, permlane P-redistribution)
  flash_attn<<<dim3(8, 64), 256, 0, stream>>>(qkvb, vt, ao);

  // 4. output projection (f32 out)
  gemm_bt<0, 0><<<dim3(D_MODEL / 128, MROWS / 128), 256, 0, stream>>>(
      ao, wos, out, tabs + 24, nullptr, MROWS, D_MODEL, D_MODEL);
}

// Round 12
// 175.685 us; speedup vs baseline: 2.1872x; 1.0548x over previous
//
#include <hip/hip_runtime.h>
#include <stdint.h>

// ---------------------------------------------------------------------------
// BitAttention round 11:
//   - gemm_dp: deep-pipeline GEMM replacing both m97-structure GEMMs.
//     128x128xBK64, 8 waves (512 thr, per-wave 64x32), double-buffered LDS,
//     depth-2 prefetch with COUNTED vmcnt(4) + raw s_barrier (T4), XOR-
//     swizzled LDS (T2), setprio (T5). 2 blocks/CU (64KB LDS), 16 waves/CU.
//   - flash_attn v10 (32x32 MFMA + permlane), prep_all, finalize: unchanged.
// ws layout (bytes):
//   [0,5120)    double partials[640]
//   [6144,6304) float tabs[40]
//   [8192,...)  xb(16M) wqkvs(12M) wos(8M) qkvb(24M) ao(16M) vt(4M)
// ---------------------------------------------------------------------------

#define D_MODEL 2048
#define S_LEN   2048
#define BATCH   2
#define NKV     8
#define HD      64
#define MROWS   (BATCH * S_LEN)   // 4096
#define NQKV    3072
#define LDQKV   3072

typedef unsigned short u16;
typedef __bf16 bf16x8 __attribute__((ext_vector_type(8)));
typedef float  f32x4  __attribute__((ext_vector_type(4)));
typedef float  f32x16 __attribute__((ext_vector_type(16)));
typedef unsigned u32x4 __attribute__((ext_vector_type(4)));

__device__ __forceinline__ u16 f2bf(float f) {
  union { float f; unsigned u; } v; v.f = f;
  unsigned r = v.u + 0x7FFFu + ((v.u >> 16) & 1u);   // RNE
  return (u16)(r >> 16);
}

__device__ __forceinline__ float exp2_fast(float x) {
  float r; asm("v_exp_f32 %0, %1" : "=v"(r) : "v"(x)); return r;
}

__device__ __forceinline__ unsigned cvt_pk_bf16(float a, float b) {
  unsigned r;
  asm("v_cvt_pk_bf16_f32 %0, %1, %2" : "=v"(r) : "v"(a), "v"(b));
  return r;
}

__device__ __forceinline__ void lds_load16(u16* lds, const u16* g) {
  __builtin_amdgcn_global_load_lds(
      (const __attribute__((address_space(1))) void*)g,
      (__attribute__((address_space(3))) void*)lds, 16, 0, 0);
}

#define SM_LOG2E 0.180336880f   // (1/sqrt(64)) * log2(e); folded into Q cols
#define THR_LOG2 11.5415603f    // 8 * log2(e)

// ---------------- fused prep: weight sign+|w| partials, x->bf16 ----------------
__global__ void prep_all(const float* __restrict__ wq, const float* __restrict__ wk,
                         const float* __restrict__ wv, const float* __restrict__ wo,
                         const float* __restrict__ x,
                         u16* __restrict__ wqkvs, u16* __restrict__ wos,
                         u16* __restrict__ xb, double* __restrict__ partials) {
  const int bid = blockIdx.x;
  const float* src; u16* dst; int n4, rb, nb; bool sgn = true;
  if (bid < 256)      { src = wq; dst = wqkvs;                  n4 = 1048576; rb = bid;       nb = 256; }
  else if (bid < 320) { src = wk; dst = wqkvs + 2048 * D_MODEL; n4 = 262144;  rb = bid - 256; nb = 64;  }
  else if (bid < 384) { src = wv; dst = wqkvs + 2560 * D_MODEL; n4 = 262144;  rb = bid - 320; nb = 64;  }
  else if (bid < 640) { src = wo; dst = wos;                    n4 = 1048576; rb = bid - 384; nb = 256; }
  else                { src = x;  dst = xb;                     n4 = 2097152; rb = bid - 640; nb = 512; sgn = false; }

  if (sgn) {
    double s = 0.0;
    for (int i = rb * 256 + threadIdx.x; i < n4; i += nb * 256) {
      float4 v = reinterpret_cast<const float4*>(src)[i];
      ushort4 o;
      o.x = v.x > 0.f ? 0x3F80 : (v.x < 0.f ? 0xBF80 : 0);
      o.y = v.y > 0.f ? 0x3F80 : (v.y < 0.f ? 0xBF80 : 0);
      o.z = v.z > 0.f ? 0x3F80 : (v.z < 0.f ? 0xBF80 : 0);
      o.w = v.w > 0.f ? 0x3F80 : (v.w < 0.f ? 0xBF80 : 0);
      reinterpret_cast<ushort4*>(dst)[i] = o;
      s += (double)fabsf(v.x) + (double)fabsf(v.y) +
           (double)fabsf(v.z) + (double)fabsf(v.w);
    }
    __shared__ double sm[256];
    sm[threadIdx.x] = s;
    __syncthreads();
    for (int off = 128; off > 0; off >>= 1) {
      if (threadIdx.x < off) sm[threadIdx.x] += sm[threadIdx.x + off];
      __syncthreads();
    }
    if (threadIdx.x == 0) partials[bid] = sm[0];
  } else {
    for (int i = rb * 256 + threadIdx.x; i < n4; i += nb * 256) {
      float4 v = reinterpret_cast<const float4*>(src)[i];
      ushort4 o;
      o.x = f2bf(v.x); o.y = f2bf(v.y); o.z = f2bf(v.z); o.w = f2bf(v.w);
      reinterpret_cast<ushort4*>(dst)[i] = o;
    }
  }
}

// 4 waves, one per weight; butterfly reduce (deterministic fixed tree).
__global__ void finalize_scales(const double* __restrict__ partials,
                                float* __restrict__ tabs) {
  __shared__ float sc_sh[4];
  const int w = threadIdx.x >> 6;
  const int lane = threadIdx.x & 63;
  const int beg[4] = {0, 256, 320, 384};
  const int cnt[4] = {256, 64, 64, 256};
  const double counts[4] = {4194304.0, 1048576.0, 1048576.0, 4194304.0};
  double s = 0.0;
  for (int i = lane; i < cnt[w]; i += 64) s += partials[beg[w] + i];
  for (int off = 1; off < 64; off <<= 1) s += __shfl_xor(s, off);
  if (lane == 0) sc_sh[w] = fmaxf((float)(s / counts[w]), 1e-5f);
  __syncthreads();
  if (threadIdx.x == 0) {
    const float s0 = sc_sh[0], s1 = sc_sh[1], s2 = sc_sh[2], s3 = sc_sh[3];
    for (int i = 0; i < 24; ++i)
      tabs[i] = (i < 16) ? s0 * SM_LOG2E : (i < 20 ? s1 : s2);
    for (int i = 0; i < 16; ++i) tabs[24 + i] = s3;
  }
}

// ---------------- deep-pipeline GEMM: C = tab[bx] * (A x Bt^T) ----------------
// 128x128 tile, BK=64, 512 threads (8 waves: 2M x 4N, per-wave 64x32 output).
// Double-buffered LDS, depth-2 prefetch, counted vmcnt(4), raw s_barrier,
// XOR-swizzled LDS staging/reads (both-sides involution, rule #21).
// VSPLIT: blocks with bx>=20 (V columns) store TRANSPOSED into vt[512][4096].
template <int OUT_BF16, int VSPLIT>
__global__ __launch_bounds__(512, 4) void gemm_dp(
    const u16* __restrict__ A, const u16* __restrict__ Bt, void* __restrict__ Cv,
    const float* __restrict__ tab, u16* __restrict__ vt, int M, int N, int K) {
  __shared__ u16 lA[2][128 * 64];
  __shared__ u16 lB[2][128 * 64];
  const int tid = threadIdx.x;
  const int lane = tid & 63, wave = tid >> 6;
  const int lo = lane & 15, hi = lane >> 4;
  const int m0 = blockIdx.y * 128, n0 = blockIdx.x * 128;
  const int wr = (wave >> 2) * 64;     // 0 or 64
  const int wc = (wave & 3) * 32;      // 0,32,64,96
  const int swl = (lo & 7) << 3;       // read-side XOR (elems)

  f32x4 acc[4][2] = {};
  const int nt = K >> 6;

  // stage K-tile kt into buffer bf: 2 A-issues + 2 B-issues per thread,
  // pre-swizzled global source -> linear LDS dest (rule #21).
#define STAGE(bf, kt)                                                          \
  {                                                                            \
    const int k0s = (kt) * 64;                                                 \
    _Pragma("unroll")                                                          \
    for (int it = 0; it < 2; ++it) {                                           \
      const int c = it * 512 + tid;                                            \
      const int row = c >> 3;                                                  \
      const int ch = (c & 7) ^ (row & 7);                                      \
      lds_load16(&lA[bf][(it * 512 + wave * 64) * 8],                          \
                 &A[(size_t)(m0 + row) * K + k0s + ch * 8]);                   \
    }                                                                          \
    _Pragma("unroll")                                                          \
    for (int it = 0; it < 2; ++it) {                                           \
      const int c = it * 512 + tid;                                            \
      const int row = c >> 3;                                                  \
      const int ch = (c & 7) ^ (row & 7);                                      \
      lds_load16(&lB[bf][(it * 512 + wave * 64) * 8],                          \
                 &Bt[(size_t)(n0 + row) * K + k0s + ch * 8]);                  \
    }                                                                          \
  }

  // prologue: prefetch tiles 0 and 1
  STAGE(0, 0)
  STAGE(1, 1)

#pragma unroll 1
  for (int kt = 0; kt < nt; ++kt) {
    const int cur = kt & 1;
    // wait for cur's 4 loads (next tile's 4 stay in flight), then sync
    if (kt + 1 < nt)
      asm volatile("s_waitcnt vmcnt(4)\n\ts_barrier" ::: "memory");
    else
      asm volatile("s_waitcnt vmcnt(0)\n\ts_barrier" ::: "memory");
    __builtin_amdgcn_sched_barrier(0);

    const u16* la = lA[cur];
    const u16* lb = lB[cur];
#pragma unroll
    for (int kk = 0; kk < 2; ++kk) {
      bf16x8 af[4], bfr[2];
#pragma unroll
      for (int i = 0; i < 4; ++i)
        af[i] = *reinterpret_cast<const bf16x8*>(
            &la[(wr + i * 16 + lo) * 64 + ((kk * 32 + hi * 8) ^ swl)]);
#pragma unroll
      for (int i = 0; i < 2; ++i)
        bfr[i] = *reinterpret_cast<const bf16x8*>(
            &lb[(wc + i * 16 + lo) * 64 + ((kk * 32 + hi * 8) ^ swl)]);
      __builtin_amdgcn_s_setprio(1);
#pragma unroll
      for (int mi = 0; mi < 4; ++mi)
#pragma unroll
        for (int ni = 0; ni < 2; ++ni)
          acc[mi][ni] = __builtin_amdgcn_mfma_f32_16x16x32_bf16(
              af[mi], bfr[ni], acc[mi][ni], 0, 0, 0);
      __builtin_amdgcn_s_setprio(0);
    }
    // all frag reads done -> safe to overwrite cur with tile kt+2
    __builtin_amdgcn_sched_barrier(0);
    asm volatile("s_barrier" ::: "memory");
    if (kt + 2 < nt) STAGE(cur, kt + 2)
  }
#undef STAGE

  const float scale = tab[blockIdx.x];
  if (VSPLIT && (int)blockIdx.x >= 20) {
    // V columns: transposed store, 4 consecutive rows (m) packed per dwordx2
#pragma unroll
    for (int mi = 0; mi < 4; ++mi) {
#pragma unroll
      for (int ni = 0; ni < 2; ++ni) {
        const int col = (n0 - 2560) + wc + ni * 16 + lo;       // 0..511
        const int row = m0 + wr + mi * 16 + hi * 4;            // mult of 4
        unsigned w01 = (unsigned)f2bf(acc[mi][ni][0] * scale) |
                       ((unsigned)f2bf(acc[mi][ni][1] * scale) << 16);
        unsigned w23 = (unsigned)f2bf(acc[mi][ni][2] * scale) |
                       ((unsigned)f2bf(acc[mi][ni][3] * scale) << 16);
        uint2 pk; pk.x = w01; pk.y = w23;
        *reinterpret_cast<uint2*>(vt + (size_t)col * MROWS + row) = pk;
      }
    }
    return;
  }
#pragma unroll
  for (int mi = 0; mi < 4; ++mi) {
#pragma unroll
    for (int ni = 0; ni < 2; ++ni) {
#pragma unroll
      for (int r = 0; r < 4; ++r) {
        const int row = m0 + wr + mi * 16 + hi * 4 + r;
        const int col = n0 + wc + ni * 16 + lo;
        const float v = acc[mi][ni][r] * scale;
        if (OUT_BF16)
          reinterpret_cast<u16*>(Cv)[(size_t)row * N + col] = f2bf(v);
        else
          reinterpret_cast<float*>(Cv)[(size_t)row * N + col] = v;
      }
    }
  }
}

// ---------------- flash attention v10 (32x32 MFMA + permlane, causal) ----------
__device__ __forceinline__ void stage_tile(u16* dst, const u16* base, int ld,
                                           int tid, int wave) {
#pragma unroll
  for (int it = 0; it < 2; ++it) {
    const int c = it * 256 + tid;
    const int row = c >> 3;
    const int ch = (c & 7) ^ (row & 7);   // pre-swizzled source (rule #21)
    lds_load16(dst + (it * 256 + wave * 64) * 8, base + (size_t)row * ld + ch * 8);
  }
}

// One KV-tile step. MASKED=1 only for the 2 diagonal tiles.
// S^T via mfma32(K,Q): lane holds q = lane&31; t = (rg&3)+8*(rg>>2)+4*hi5+32*nf.
#define TILE_BODY(MASKED)                                                      \
  {                                                                            \
    const int t0 = ti * 64;                                                    \
    const int cur = ti & 1;                                                    \
    u16* lKc = (u16*)lK[cur];                                                  \
    u16* lVc = (u16*)lV[cur];                                                  \
    f32x16 sacc[2] = {};                                                       \
    __builtin_amdgcn_s_setprio(1);                                             \
    _Pragma("unroll")                                                          \
    for (int w = 0; w < 4; ++w) {                                              \
      _Pragma("unroll")                                                        \
      for (int nf = 0; nf < 2; ++nf) {                                         \
        bf16x8 kf = *reinterpret_cast<const bf16x8*>(                          \
            &lKc[(nf * 32 + q31) * 64 + ((w * 16 + hi5 * 8) ^ swl)]);          \
        sacc[nf] = __builtin_amdgcn_mfma_f32_32x32x16_bf16(                    \
            kf, qf[w], sacc[nf], 0, 0, 0);                                     \
      }                                                                        \
    }                                                                          \
    __builtin_amdgcn_s_setprio(0);                                             \
    if (ti + 1 < nt) {                                                         \
      stage_tile(lK[cur ^ 1], Kb + (size_t)(brow + t0 + 64) * LDQKV, LDQKV,    \
                 tid, wave);                                                   \
      stage_tile(lV[cur ^ 1], Vb + t0 + 64, MROWS, tid, wave);                 \
    }                                                                          \
    if (MASKED) {                                                              \
      _Pragma("unroll")                                                        \
      for (int nf = 0; nf < 2; ++nf) {                                         \
        _Pragma("unroll")                                                      \
        for (int rg = 0; rg < 16; ++rg) {                                      \
          const int tg = t0 + nf * 32 + (rg >> 2) * 8 + hi5 * 4 + (rg & 3);    \
          if (tg > qg) sacc[nf][rg] = -1e30f;                                  \
        }                                                                      \
      }                                                                        \
    }                                                                          \
    float mt = -1e30f;                                                         \
    _Pragma("unroll")                                                          \
    for (int nf = 0; nf < 2; ++nf) {                                           \
      _Pragma("unroll")                                                        \
      for (int rg = 0; rg < 16; ++rg) mt = fmaxf(mt, sacc[nf][rg]);            \
    }                                                                          \
    mt = fmaxf(mt, __shfl_xor(mt, 32));                                        \
    if (!__all((int)(mt <= m_run + THR_LOG2))) {                               \
      const float mn = fmaxf(m_run, mt);                                       \
      const float alpha = exp2_fast(m_run - mn);                               \
      m_run = mn;                                                              \
      l_lane *= alpha;                                                         \
      _Pragma("unroll")                                                        \
      for (int nf = 0; nf < 2; ++nf) {                                         \
        _Pragma("unroll")                                                      \
        for (int rg = 0; rg < 16; ++rg) oacc[nf][rg] *= alpha;                 \
      }                                                                        \
    }                                                                          \
    unsigned pk[2][8];                                                         \
    _Pragma("unroll")                                                          \
    for (int nf = 0; nf < 2; ++nf) {                                           \
      _Pragma("unroll")                                                        \
      for (int c = 0; c < 4; ++c) {                                            \
        const float e0 = exp2_fast(sacc[nf][4 * c + 0] - m_run);               \
        const float e1 = exp2_fast(sacc[nf][4 * c + 1] - m_run);               \
        const float e2 = exp2_fast(sacc[nf][4 * c + 2] - m_run);               \
        const float e3 = exp2_fast(sacc[nf][4 * c + 3] - m_run);               \
        l_lane += (e0 + e1) + (e2 + e3);                                       \
        pk[nf][2 * c + 0] = cvt_pk_bf16(e0, e1);                               \
        pk[nf][2 * c + 1] = cvt_pk_bf16(e2, e3);                               \
      }                                                                        \
    }                                                                          \
    __builtin_amdgcn_s_setprio(1);                                             \
    _Pragma("unroll")                                                          \
    for (int w = 0; w < 4; ++w) {                                              \
      const int nf = w >> 1, c4 = (w & 1) * 4;                                 \
      unsigned a0 = pk[nf][c4 + 0], a1 = pk[nf][c4 + 1];                       \
      unsigned b0 = pk[nf][c4 + 2], b1 = pk[nf][c4 + 3];                       \
      asm volatile("v_permlane32_swap_b32 %0, %1" : "+v"(a0), "+v"(b0));       \
      asm volatile("v_permlane32_swap_b32 %0, %1" : "+v"(a1), "+v"(b1));       \
      u32x4 pw; pw.x = a0; pw.y = a1; pw.z = b0; pw.w = b1;                    \
      bf16x8 pfr = *reinterpret_cast<const bf16x8*>(&pw);                      \
      _Pragma("unroll")                                                        \
      for (int nfo = 0; nfo < 2; ++nfo) {                                      \
        bf16x8 vf = *reinterpret_cast<const bf16x8*>(                          \
            &lVc[(nfo * 32 + q31) * 64 + ((w * 16 + hi5 * 8) ^ swl)]);         \
        oacc[nfo] = __builtin_amdgcn_mfma_f32_32x32x16_bf16(                   \
            vf, pfr, oacc[nfo], 0, 0, 0);                                      \
      }                                                                        \
    }                                                                          \
    __builtin_amdgcn_s_setprio(0);                                             \
    __syncthreads();                                                           \
  }

__global__ __launch_bounds__(256, 2) void flash_attn(
    const u16* __restrict__ QKV, const u16* __restrict__ VT,
    u16* __restrict__ Og) {
  __shared__ u16 lK[2][64 * 64];    // [t][d], XOR-swizzled chunks
  __shared__ u16 lV[2][64 * 64];    // [d][t], XOR-swizzled chunks

  const int tid = threadIdx.x;
  const int lane = tid & 63, wave = tid >> 6;
  const int q31 = lane & 31, hi5 = lane >> 5;
  // XCD group pinning (round-8): each (b,kv) group's 32 blocks on one XCD.
  const int lin = (int)blockIdx.y * 8 + (int)blockIdx.x;   // 0..511
  const int xcd = lin & 7, slot = lin >> 3;
  const int G = xcd * 2 + (slot >> 5);    // 0..15 = (b, kv)
  const int wb = slot & 31;               // 0..31 = (g_h, lbx)
  const int b = G >> 3, kv = G & 7;
  const int h = kv * 4 + (wb >> 3);
  const int lbx = wb & 7;
  const int brow = b * S_LEN;
  const u16* Q  = QKV + h * HD;
  const u16* Kb = QKV + 2048 + kv * HD;                   // row stride LDQKV
  const u16* Vb = VT + (size_t)(kv * HD) * MROWS + brow;  // row d, stride MROWS
  const int swl = (lane & 7) << 3;

#pragma unroll 1
  for (int pi = 0; pi < 2; ++pi) {
    const int qt = pi == 0 ? lbx : (15 - lbx);
    const int q0 = qt * 128;
    const int q0w = q0 + wave * 32;
    const int nt = 2 * qt + 2;
    const int qg = q0w + q31;          // lane's q row

    // Q fragments: lane holds Q[q][16w + 8*hi5 .. +8] per window w
    bf16x8 qf[4];
    {
      const size_t qr = (size_t)(brow + q0w + q31) * LDQKV;
#pragma unroll
      for (int w = 0; w < 4; ++w)
        qf[w] = *reinterpret_cast<const bf16x8*>(&Q[qr + w * 16 + hi5 * 8]);
    }

    f32x16 oacc[2] = {};
    float m_run = -1e30f, l_lane = 0.f;

    // prologue: stage tile 0 into buffer 0
    stage_tile(lK[0], Kb + (size_t)brow * LDQKV, LDQKV, tid, wave);
    stage_tile(lV[0], Vb, MROWS, tid, wave);
    __syncthreads();

    // full tiles: no causal masking needed (t0+64 <= q0)
#pragma unroll 1
    for (int ti = 0; ti < 2 * qt; ++ti) TILE_BODY(0)
    // diagonal tiles (2): per-element masking
#pragma unroll 1
    for (int ti = 2 * qt; ti < nt; ++ti) TILE_BODY(1)

    // ---- epilogue: l across lane pair, lane-local normalize, packed store ----
    {
      float ls = l_lane;
      ls += __shfl_xor(ls, 32);
      const float inv = 1.f / ls;
#pragma unroll
      for (int nfo = 0; nfo < 2; ++nfo) {
#pragma unroll
        for (int c = 0; c < 4; ++c) {
          const unsigned u0 = cvt_pk_bf16(oacc[nfo][4 * c + 0] * inv,
                                          oacc[nfo][4 * c + 1] * inv);
          const unsigned u1 = cvt_pk_bf16(oacc[nfo][4 * c + 2] * inv,
                                          oacc[nfo][4 * c + 3] * inv);
          const int d = nfo * 32 + c * 8 + hi5 * 4;
          uint2 st; st.x = u0; st.y = u1;
          *reinterpret_cast<uint2*>(
              &Og[(size_t)(brow + q0w + q31) * D_MODEL + h * HD + d]) = st;
        }
      }
    }
  }
}

// ---------------- launcher ----------------
extern "C" void kernel_launch(void* const* d_in, const int* in_sizes, int n_in,
                              void* d_out, int out_size, void* d_ws, size_t ws_size,
                              hipStream_t stream) {
  (void)in_sizes; (void)n_in; (void)out_size; (void)ws_size;
  const float* x  = (const float*)d_in[0];
  const float* wq = (const float*)d_in[1];
  const float* wk = (const float*)d_in[2];
  const float* wv = (const float*)d_in[3];
  const float* wo = (const float*)d_in[4];
  float* out = (float*)d_out;
  char* ws = (char*)d_ws;

  double* partials = (double*)ws;            // 640 * 8 B
  float* tabs = (float*)(ws + 6144);         // 40 floats
  size_t off = 8192;
  u16* xb    = (u16*)(ws + off); off += (size_t)MROWS * D_MODEL * 2;
  u16* wqkvs = (u16*)(ws + off); off += (size_t)NQKV * D_MODEL * 2;
  u16* wos   = (u16*)(ws + off); off += (size_t)D_MODEL * D_MODEL * 2;
  u16* qkvb  = (u16*)(ws + off); off += (size_t)MROWS * NQKV * 2;
  u16* ao    = (u16*)(ws + off); off += (size_t)MROWS * D_MODEL * 2;
  u16* vt    = (u16*)(ws + off); off += (size_t)512 * MROWS * 2;

  // 1. fused prep: weight signs + |w| partials + x->bf16
  prep_all<<<1152, 256, 0, stream>>>(wq, wk, wv, wo, x, wqkvs, wos, xb, partials);
  finalize_scales<<<1, 256, 0, stream>>>(partials, tabs);

  // 2. fused QKV projection (deep-pipeline); V columns transposed into vt
  gemm_dp<1, 1><<<dim3(NQKV / 128, MROWS / 128), 512, 0, stream>>>(
      xb, wqkvs, qkvb, tabs, vt, MROWS, NQKV, D_MODEL);

  // 3. GQA causal flash attention (32x32 MFMA, permlane P-redistribution)
  flash_attn<<<dim3(8, 64), 256, 0, stream>>>(qkvb, vt, ao);

  // 4. output projection (deep-pipeline, f32 out)
  gemm_dp<0, 0><<<dim3(D_MODEL / 128, MROWS / 128), 512, 0, stream>>>(
      ao, wos, out, tabs + 24, nullptr, MROWS, D_MODEL, D_MODEL);
}

// Round 13
// 158.414 us; speedup vs baseline: 2.4257x; 1.1090x over previous
//
#include <hip/hip_runtime.h>
#include <stdint.h>

// ---------------------------------------------------------------------------
// BitAttention round 12:
//   - gemm_dp<BN,...>: templated deep-pipeline GEMM. QKV uses BN=192 ->
//     grid (16,32)=512 blocks = EXACTLY 2/CU (kills the 1.5-round tail that
//     held QKV at 75us); per-wave 64x48 (0.58 LDS-reads/MFMA). O-proj BN=128
//     (already 512 blocks). Counted vmcnt + raw s_barrier + T2 swizzle kept.
//     Scale table reduced to 4 scalars; per-frag Q/K/V select + V^T store.
//   - flash_attn v10 (32x32 MFMA + permlane), prep_all: unchanged.
// ws layout (bytes):
//   [0,5120)    double partials[640]
//   [6144,6304) float tabs[4]: sq*log2e, sk, sv, so
//   [8192,...)  xb(16M) wqkvs(12M) wos(8M) qkvb(24M) ao(16M) vt(4M)
// ---------------------------------------------------------------------------

#define D_MODEL 2048
#define S_LEN   2048
#define BATCH   2
#define NKV     8
#define HD      64
#define MROWS   (BATCH * S_LEN)   // 4096
#define NQKV    3072
#define LDQKV   3072

typedef unsigned short u16;
typedef __bf16 bf16x8 __attribute__((ext_vector_type(8)));
typedef float  f32x4  __attribute__((ext_vector_type(4)));
typedef float  f32x16 __attribute__((ext_vector_type(16)));
typedef unsigned u32x4 __attribute__((ext_vector_type(4)));

__device__ __forceinline__ u16 f2bf(float f) {
  union { float f; unsigned u; } v; v.f = f;
  unsigned r = v.u + 0x7FFFu + ((v.u >> 16) & 1u);   // RNE
  return (u16)(r >> 16);
}

__device__ __forceinline__ float exp2_fast(float x) {
  float r; asm("v_exp_f32 %0, %1" : "=v"(r) : "v"(x)); return r;
}

__device__ __forceinline__ unsigned cvt_pk_bf16(float a, float b) {
  unsigned r;
  asm("v_cvt_pk_bf16_f32 %0, %1, %2" : "=v"(r) : "v"(a), "v"(b));
  return r;
}

__device__ __forceinline__ void lds_load16(u16* lds, const u16* g) {
  __builtin_amdgcn_global_load_lds(
      (const __attribute__((address_space(1))) void*)g,
      (__attribute__((address_space(3))) void*)lds, 16, 0, 0);
}

#define SM_LOG2E 0.180336880f   // (1/sqrt(64)) * log2(e); folded into Q cols
#define THR_LOG2 11.5415603f    // 8 * log2(e)

// ---------------- fused prep: weight sign+|w| partials, x->bf16 ----------------
__global__ void prep_all(const float* __restrict__ wq, const float* __restrict__ wk,
                         const float* __restrict__ wv, const float* __restrict__ wo,
                         const float* __restrict__ x,
                         u16* __restrict__ wqkvs, u16* __restrict__ wos,
                         u16* __restrict__ xb, double* __restrict__ partials) {
  const int bid = blockIdx.x;
  const float* src; u16* dst; int n4, rb, nb; bool sgn = true;
  if (bid < 256)      { src = wq; dst = wqkvs;                  n4 = 1048576; rb = bid;       nb = 256; }
  else if (bid < 320) { src = wk; dst = wqkvs + 2048 * D_MODEL; n4 = 262144;  rb = bid - 256; nb = 64;  }
  else if (bid < 384) { src = wv; dst = wqkvs + 2560 * D_MODEL; n4 = 262144;  rb = bid - 320; nb = 64;  }
  else if (bid < 640) { src = wo; dst = wos;                    n4 = 1048576; rb = bid - 384; nb = 256; }
  else                { src = x;  dst = xb;                     n4 = 2097152; rb = bid - 640; nb = 512; sgn = false; }

  if (sgn) {
    double s = 0.0;
    for (int i = rb * 256 + threadIdx.x; i < n4; i += nb * 256) {
      float4 v = reinterpret_cast<const float4*>(src)[i];
      ushort4 o;
      o.x = v.x > 0.f ? 0x3F80 : (v.x < 0.f ? 0xBF80 : 0);
      o.y = v.y > 0.f ? 0x3F80 : (v.y < 0.f ? 0xBF80 : 0);
      o.z = v.z > 0.f ? 0x3F80 : (v.z < 0.f ? 0xBF80 : 0);
      o.w = v.w > 0.f ? 0x3F80 : (v.w < 0.f ? 0xBF80 : 0);
      reinterpret_cast<ushort4*>(dst)[i] = o;
      s += (double)fabsf(v.x) + (double)fabsf(v.y) +
           (double)fabsf(v.z) + (double)fabsf(v.w);
    }
    __shared__ double sm[256];
    sm[threadIdx.x] = s;
    __syncthreads();
    for (int off = 128; off > 0; off >>= 1) {
      if (threadIdx.x < off) sm[threadIdx.x] += sm[threadIdx.x + off];
      __syncthreads();
    }
    if (threadIdx.x == 0) partials[bid] = sm[0];
  } else {
    for (int i = rb * 256 + threadIdx.x; i < n4; i += nb * 256) {
      float4 v = reinterpret_cast<const float4*>(src)[i];
      ushort4 o;
      o.x = f2bf(v.x); o.y = f2bf(v.y); o.z = f2bf(v.z); o.w = f2bf(v.w);
      reinterpret_cast<ushort4*>(dst)[i] = o;
    }
  }
}

// 4 waves, one per weight; butterfly reduce (deterministic fixed tree).
// tabs[0]=sq*log2e, tabs[1]=sk, tabs[2]=sv, tabs[3]=so
__global__ void finalize_scales(const double* __restrict__ partials,
                                float* __restrict__ tabs) {
  __shared__ float sc_sh[4];
  const int w = threadIdx.x >> 6;
  const int lane = threadIdx.x & 63;
  const int beg[4] = {0, 256, 320, 384};
  const int cnt[4] = {256, 64, 64, 256};
  const double counts[4] = {4194304.0, 1048576.0, 1048576.0, 4194304.0};
  double s = 0.0;
  for (int i = lane; i < cnt[w]; i += 64) s += partials[beg[w] + i];
  for (int off = 1; off < 64; off <<= 1) s += __shfl_xor(s, off);
  if (lane == 0) sc_sh[w] = fmaxf((float)(s / counts[w]), 1e-5f);
  __syncthreads();
  if (threadIdx.x == 0) {
    tabs[0] = sc_sh[0] * SM_LOG2E;
    tabs[1] = sc_sh[1];
    tabs[2] = sc_sh[2];
    tabs[3] = sc_sh[3];
  }
}

// ---------------- deep-pipeline GEMM (templated BN) ----------------
// 128xBN tile, BK=64, 512 threads (8 waves: 2M x 4N, per-wave 64 x BN/4).
// Double-buffered LDS, depth-2 prefetch, counted vmcnt, raw s_barrier,
// XOR-swizzled LDS (rule #21). QKVMODE: per-frag scale select (Q|K|V) and
// V-column frags (col>=2560) stored TRANSPOSED into vt[512][4096] only.
template <int BN, int OUT_BF16, int QKVMODE>
__global__ __launch_bounds__(512, 4) void gemm_dp(
    const u16* __restrict__ A, const u16* __restrict__ Bt, void* __restrict__ Cv,
    const float* __restrict__ tabs4, u16* __restrict__ vt, int M, int N, int K) {
  constexpr int WN = BN / 4;              // per-wave N: 48 or 32
  constexpr int NFR = WN / 16;            // 3 or 2
  constexpr int BITER = BN / 64;          // B stage issues: 3 or 2
  constexpr int STEADY = 2 + BITER;       // in-flight loads of one tile
  __shared__ u16 lA[2][128 * 64];
  __shared__ u16 lB[2][BN * 64];
  const int tid = threadIdx.x;
  const int lane = tid & 63, wave = tid >> 6;
  const int lo = lane & 15, hi = lane >> 4;
  const int m0 = blockIdx.y * 128, n0 = blockIdx.x * BN;
  const int wr = (wave >> 2) * 64;        // 0 or 64
  const int wc = (wave & 3) * WN;
  const int swl = (lo & 7) << 3;          // read-side XOR (elems)

  f32x4 acc[4][NFR] = {};
  const int nt = K >> 6;

  auto STAGE = [&](int bf, int kt) {
    const int k0s = kt * 64;
#pragma unroll
    for (int it = 0; it < 2; ++it) {
      const int c = it * 512 + tid;
      const int row = c >> 3;
      const int ch = (c & 7) ^ (row & 7);
      lds_load16(&lA[bf][(it * 512 + wave * 64) * 8],
                 &A[(size_t)(m0 + row) * K + k0s + ch * 8]);
    }
#pragma unroll
    for (int it = 0; it < BITER; ++it) {
      const int c = it * 512 + tid;
      const int row = c >> 3;
      const int ch = (c & 7) ^ (row & 7);
      lds_load16(&lB[bf][(it * 512 + wave * 64) * 8],
                 &Bt[(size_t)(n0 + row) * K + k0s + ch * 8]);
    }
  };

  // prologue: prefetch tiles 0 and 1
  STAGE(0, 0);
  STAGE(1, 1);

#pragma unroll 1
  for (int kt = 0; kt < nt; ++kt) {
    const int cur = kt & 1;
    // wait for cur's loads (next tile's stay in flight), then sync
    if (kt + 1 < nt) {
      if constexpr (BITER == 3)
        asm volatile("s_waitcnt vmcnt(5)\n\ts_barrier" ::: "memory");
      else
        asm volatile("s_waitcnt vmcnt(4)\n\ts_barrier" ::: "memory");
    } else {
      asm volatile("s_waitcnt vmcnt(0)\n\ts_barrier" ::: "memory");
    }
    __builtin_amdgcn_sched_barrier(0);

    const u16* la = lA[cur];
    const u16* lb = lB[cur];
#pragma unroll
    for (int kk = 0; kk < 2; ++kk) {
      bf16x8 af[4], bfr[NFR];
#pragma unroll
      for (int i = 0; i < 4; ++i)
        af[i] = *reinterpret_cast<const bf16x8*>(
            &la[(wr + i * 16 + lo) * 64 + ((kk * 32 + hi * 8) ^ swl)]);
#pragma unroll
      for (int i = 0; i < NFR; ++i)
        bfr[i] = *reinterpret_cast<const bf16x8*>(
            &lb[(wc + i * 16 + lo) * 64 + ((kk * 32 + hi * 8) ^ swl)]);
      __builtin_amdgcn_s_setprio(1);
#pragma unroll
      for (int mi = 0; mi < 4; ++mi)
#pragma unroll
        for (int ni = 0; ni < NFR; ++ni)
          acc[mi][ni] = __builtin_amdgcn_mfma_f32_16x16x32_bf16(
              af[mi], bfr[ni], acc[mi][ni], 0, 0, 0);
      __builtin_amdgcn_s_setprio(0);
    }
    // all frag reads done -> safe to overwrite cur with tile kt+2
    __builtin_amdgcn_sched_barrier(0);
    asm volatile("s_barrier" ::: "memory");
    if (kt + 2 < nt) STAGE(cur, kt + 2);
  }

  const float s0 = tabs4[0];
#pragma unroll
  for (int mi = 0; mi < 4; ++mi) {
#pragma unroll
    for (int ni = 0; ni < NFR; ++ni) {
      const int col0 = n0 + wc + ni * 16;   // frag-uniform (16-aligned)
      float scale = s0;
      if (QKVMODE) scale = col0 < 2048 ? s0 : (col0 < 2560 ? tabs4[1] : tabs4[2]);
      if (QKVMODE && col0 >= 2560) {
        // V frag: transposed store, 4 consecutive rows packed per dwordx2
        const int vcol = col0 - 2560 + lo;               // 0..511
        const int row = m0 + wr + mi * 16 + hi * 4;      // mult of 4
        unsigned w01 = cvt_pk_bf16(acc[mi][ni][0] * scale, acc[mi][ni][1] * scale);
        unsigned w23 = cvt_pk_bf16(acc[mi][ni][2] * scale, acc[mi][ni][3] * scale);
        uint2 pk; pk.x = w01; pk.y = w23;
        *reinterpret_cast<uint2*>(vt + (size_t)vcol * MROWS + row) = pk;
      } else {
#pragma unroll
        for (int r = 0; r < 4; ++r) {
          const int row = m0 + wr + mi * 16 + hi * 4 + r;
          const int col = col0 + lo;
          const float v = acc[mi][ni][r] * scale;
          if (OUT_BF16)
            reinterpret_cast<u16*>(Cv)[(size_t)row * N + col] = f2bf(v);
          else
            reinterpret_cast<float*>(Cv)[(size_t)row * N + col] = v;
        }
      }
    }
  }
}

// ---------------- flash attention v10 (32x32 MFMA + permlane, causal) ----------
__device__ __forceinline__ void stage_tile(u16* dst, const u16* base, int ld,
                                           int tid, int wave) {
#pragma unroll
  for (int it = 0; it < 2; ++it) {
    const int c = it * 256 + tid;
    const int row = c >> 3;
    const int ch = (c & 7) ^ (row & 7);   // pre-swizzled source (rule #21)
    lds_load16(dst + (it * 256 + wave * 64) * 8, base + (size_t)row * ld + ch * 8);
  }
}

// One KV-tile step. MASKED=1 only for the 2 diagonal tiles.
// S^T via mfma32(K,Q): lane holds q = lane&31; t = (rg&3)+8*(rg>>2)+4*hi5+32*nf.
#define TILE_BODY(MASKED)                                                      \
  {                                                                            \
    const int t0 = ti * 64;                                                    \
    const int cur = ti & 1;                                                    \
    u16* lKc = (u16*)lK[cur];                                                  \
    u16* lVc = (u16*)lV[cur];                                                  \
    f32x16 sacc[2] = {};                                                       \
    __builtin_amdgcn_s_setprio(1);                                             \
    _Pragma("unroll")                                                          \
    for (int w = 0; w < 4; ++w) {                                              \
      _Pragma("unroll")                                                        \
      for (int nf = 0; nf < 2; ++nf) {                                         \
        bf16x8 kf = *reinterpret_cast<const bf16x8*>(                          \
            &lKc[(nf * 32 + q31) * 64 + ((w * 16 + hi5 * 8) ^ swl)]);          \
        sacc[nf] = __builtin_amdgcn_mfma_f32_32x32x16_bf16(                    \
            kf, qf[w], sacc[nf], 0, 0, 0);                                     \
      }                                                                        \
    }                                                                          \
    __builtin_amdgcn_s_setprio(0);                                             \
    if (ti + 1 < nt) {                                                         \
      stage_tile(lK[cur ^ 1], Kb + (size_t)(brow + t0 + 64) * LDQKV, LDQKV,    \
                 tid, wave);                                                   \
      stage_tile(lV[cur ^ 1], Vb + t0 + 64, MROWS, tid, wave);                 \
    }                                                                          \
    if (MASKED) {                                                              \
      _Pragma("unroll")                                                        \
      for (int nf = 0; nf < 2; ++nf) {                                         \
        _Pragma("unroll")                                                      \
        for (int rg = 0; rg < 16; ++rg) {                                      \
          const int tg = t0 + nf * 32 + (rg >> 2) * 8 + hi5 * 4 + (rg & 3);    \
          if (tg > qg) sacc[nf][rg] = -1e30f;                                  \
        }                                                                      \
      }                                                                        \
    }                                                                          \
    float mt = -1e30f;                                                         \
    _Pragma("unroll")                                                          \
    for (int nf = 0; nf < 2; ++nf) {                                           \
      _Pragma("unroll")                                                        \
      for (int rg = 0; rg < 16; ++rg) mt = fmaxf(mt, sacc[nf][rg]);            \
    }                                                                          \
    mt = fmaxf(mt, __shfl_xor(mt, 32));                                        \
    if (!__all((int)(mt <= m_run + THR_LOG2))) {                               \
      const float mn = fmaxf(m_run, mt);                                       \
      const float alpha = exp2_fast(m_run - mn);                               \
      m_run = mn;                                                              \
      l_lane *= alpha;                                                         \
      _Pragma("unroll")                                                        \
      for (int nf = 0; nf < 2; ++nf) {                                         \
        _Pragma("unroll")                                                      \
        for (int rg = 0; rg < 16; ++rg) oacc[nf][rg] *= alpha;                 \
      }                                                                        \
    }                                                                          \
    unsigned pk[2][8];                                                         \
    _Pragma("unroll")                                                          \
    for (int nf = 0; nf < 2; ++nf) {                                           \
      _Pragma("unroll")                                                        \
      for (int c = 0; c < 4; ++c) {                                            \
        const float e0 = exp2_fast(sacc[nf][4 * c + 0] - m_run);               \
        const float e1 = exp2_fast(sacc[nf][4 * c + 1] - m_run);               \
        const float e2 = exp2_fast(sacc[nf][4 * c + 2] - m_run);               \
        const float e3 = exp2_fast(sacc[nf][4 * c + 3] - m_run);               \
        l_lane += (e0 + e1) + (e2 + e3);                                       \
        pk[nf][2 * c + 0] = cvt_pk_bf16(e0, e1);                               \
        pk[nf][2 * c + 1] = cvt_pk_bf16(e2, e3);                               \
      }                                                                        \
    }                                                                          \
    __builtin_amdgcn_s_setprio(1);                                             \
    _Pragma("unroll")                                                          \
    for (int w = 0; w < 4; ++w) {                                              \
      const int nf = w >> 1, c4 = (w & 1) * 4;                                 \
      unsigned a0 = pk[nf][c4 + 0], a1 = pk[nf][c4 + 1];                       \
      unsigned b0 = pk[nf][c4 + 2], b1 = pk[nf][c4 + 3];                       \
      asm volatile("v_permlane32_swap_b32 %0, %1" : "+v"(a0), "+v"(b0));       \
      asm volatile("v_permlane32_swap_b32 %0, %1" : "+v"(a1), "+v"(b1));       \
      u32x4 pw; pw.x = a0; pw.y = a1; pw.z = b0; pw.w = b1;                    \
      bf16x8 pfr = *reinterpret_cast<const bf16x8*>(&pw);                      \
      _Pragma("unroll")                                                        \
      for (int nfo = 0; nfo < 2; ++nfo) {                                      \
        bf16x8 vf = *reinterpret_cast<const bf16x8*>(                          \
            &lVc[(nfo * 32 + q31) * 64 + ((w * 16 + hi5 * 8) ^ swl)]);         \
        oacc[nfo] = __builtin_amdgcn_mfma_f32_32x32x16_bf16(                   \
            vf, pfr, oacc[nfo], 0, 0, 0);                                      \
      }                                                                        \
    }                                                                          \
    __builtin_amdgcn_s_setprio(0);                                             \
    __syncthreads();                                                           \
  }

__global__ __launch_bounds__(256, 2) void flash_attn(
    const u16* __restrict__ QKV, const u16* __restrict__ VT,
    u16* __restrict__ Og) {
  __shared__ u16 lK[2][64 * 64];    // [t][d], XOR-swizzled chunks
  __shared__ u16 lV[2][64 * 64];    // [d][t], XOR-swizzled chunks

  const int tid = threadIdx.x;
  const int lane = tid & 63, wave = tid >> 6;
  const int q31 = lane & 31, hi5 = lane >> 5;
  // XCD group pinning (round-8): each (b,kv) group's 32 blocks on one XCD.
  const int lin = (int)blockIdx.y * 8 + (int)blockIdx.x;   // 0..511
  const int xcd = lin & 7, slot = lin >> 3;
  const int G = xcd * 2 + (slot >> 5);    // 0..15 = (b, kv)
  const int wb = slot & 31;               // 0..31 = (g_h, lbx)
  const int b = G >> 3, kv = G & 7;
  const int h = kv * 4 + (wb >> 3);
  const int lbx = wb & 7;
  const int brow = b * S_LEN;
  const u16* Q  = QKV + h * HD;
  const u16* Kb = QKV + 2048 + kv * HD;                   // row stride LDQKV
  const u16* Vb = VT + (size_t)(kv * HD) * MROWS + brow;  // row d, stride MROWS
  const int swl = (lane & 7) << 3;

#pragma unroll 1
  for (int pi = 0; pi < 2; ++pi) {
    const int qt = pi == 0 ? lbx : (15 - lbx);
    const int q0 = qt * 128;
    const int q0w = q0 + wave * 32;
    const int nt = 2 * qt + 2;
    const int qg = q0w + q31;          // lane's q row

    // Q fragments: lane holds Q[q][16w + 8*hi5 .. +8] per window w
    bf16x8 qf[4];
    {
      const size_t qr = (size_t)(brow + q0w + q31) * LDQKV;
#pragma unroll
      for (int w = 0; w < 4; ++w)
        qf[w] = *reinterpret_cast<const bf16x8*>(&Q[qr + w * 16 + hi5 * 8]);
    }

    f32x16 oacc[2] = {};
    float m_run = -1e30f, l_lane = 0.f;

    // prologue: stage tile 0 into buffer 0
    stage_tile(lK[0], Kb + (size_t)brow * LDQKV, LDQKV, tid, wave);
    stage_tile(lV[0], Vb, MROWS, tid, wave);
    __syncthreads();

    // full tiles: no causal masking needed (t0+64 <= q0)
#pragma unroll 1
    for (int ti = 0; ti < 2 * qt; ++ti) TILE_BODY(0)
    // diagonal tiles (2): per-element masking
#pragma unroll 1
    for (int ti = 2 * qt; ti < nt; ++ti) TILE_BODY(1)

    // ---- epilogue: l across lane pair, lane-local normalize, packed store ----
    {
      float ls = l_lane;
      ls += __shfl_xor(ls, 32);
      const float inv = 1.f / ls;
#pragma unroll
      for (int nfo = 0; nfo < 2; ++nfo) {
#pragma unroll
        for (int c = 0; c < 4; ++c) {
          const unsigned u0 = cvt_pk_bf16(oacc[nfo][4 * c + 0] * inv,
                                          oacc[nfo][4 * c + 1] * inv);
          const unsigned u1 = cvt_pk_bf16(oacc[nfo][4 * c + 2] * inv,
                                          oacc[nfo][4 * c + 3] * inv);
          const int d = nfo * 32 + c * 8 + hi5 * 4;
          uint2 st; st.x = u0; st.y = u1;
          *reinterpret_cast<uint2*>(
              &Og[(size_t)(brow + q0w + q31) * D_MODEL + h * HD + d]) = st;
        }
      }
    }
  }
}

// ---------------- launcher ----------------
extern "C" void kernel_launch(void* const* d_in, const int* in_sizes, int n_in,
                              void* d_out, int out_size, void* d_ws, size_t ws_size,
                              hipStream_t stream) {
  (void)in_sizes; (void)n_in; (void)out_size; (void)ws_size;
  const float* x  = (const float*)d_in[0];
  const float* wq = (const float*)d_in[1];
  const float* wk = (const float*)d_in[2];
  const float* wv = (const float*)d_in[3];
  const float* wo = (const float*)d_in[4];
  float* out = (float*)d_out;
  char* ws = (char*)d_ws;

  double* partials = (double*)ws;            // 640 * 8 B
  float* tabs = (float*)(ws + 6144);         // 4 floats
  size_t off = 8192;
  u16* xb    = (u16*)(ws + off); off += (size_t)MROWS * D_MODEL * 2;
  u16* wqkvs = (u16*)(ws + off); off += (size_t)NQKV * D_MODEL * 2;
  u16* wos   = (u16*)(ws + off); off += (size_t)D_MODEL * D_MODEL * 2;
  u16* qkvb  = (u16*)(ws + off); off += (size_t)MROWS * NQKV * 2;
  u16* ao    = (u16*)(ws + off); off += (size_t)MROWS * D_MODEL * 2;
  u16* vt    = (u16*)(ws + off); off += (size_t)512 * MROWS * 2;

  // 1. fused prep: weight signs + |w| partials + x->bf16
  prep_all<<<1152, 256, 0, stream>>>(wq, wk, wv, wo, x, wqkvs, wos, xb, partials);
  finalize_scales<<<1, 256, 0, stream>>>(partials, tabs);

  // 2. fused QKV projection (BN=192 -> 512 blocks, exactly 2/CU)
  gemm_dp<192, 1, 1><<<dim3(NQKV / 192, MROWS / 128), 512, 0, stream>>>(
      xb, wqkvs, qkvb, tabs, vt, MROWS, NQKV, D_MODEL);

  // 3. GQA causal flash attention (32x32 MFMA, permlane P-redistribution)
  flash_attn<<<dim3(8, 64), 256, 0, stream>>>(qkvb, vt, ao);

  // 4. output projection (BN=128 -> 512 blocks, f32 out)
  gemm_dp<128, 0, 0><<<dim3(D_MODEL / 128, MROWS / 128), 512, 0, stream>>>(
      ao, wos, out, tabs + 3, nullptr, MROWS, D_MODEL, D_MODEL);
}